// Round 1
// baseline (1412.823 us; speedup 1.0000x reference)
//
#include <hip/hip_runtime.h>
#include <cmath>

#define NNODES 100000
#define NEDGES 3200000
#define NFEAT 256
#define NCLASS 40

// ---------------------------------------------------------------------------
// Detect whether edge_index arrived as int64 (stride 2 in int32 units) or
// int32 (stride 1). int64 values < 2^31 have all-zero high dwords.
__global__ void detect_kernel(const int* __restrict__ eidx, int* __restrict__ flag) {
    __shared__ int odd_nz;
    if (threadIdx.x == 0) odd_nz = 0;
    __syncthreads();
    int local = 0;
    for (int i = threadIdx.x; i < 2048; i += blockDim.x) {
        if (eidx[2 * i + 1] != 0) local = 1;
    }
    if (local) atomicOr(&odd_nz, 1);
    __syncthreads();
    if (threadIdx.x == 0) *flag = odd_nz ? 1 : 2;
}

// ---------------------------------------------------------------------------
// deg[col] += w  (self-loop +1 folded into dinv kernel)
__global__ void deg_kernel(const int* __restrict__ eidx, const float* __restrict__ w,
                           float* __restrict__ deg, const int* __restrict__ flag) {
    int e = blockIdx.x * blockDim.x + threadIdx.x;
    if (e >= NEDGES) return;
    int stride = *flag;
    int col = eidx[((long long)NEDGES + e) * (long long)stride];
    unsafeAtomicAdd(&deg[col], w[e]);
}

__global__ void dinv_kernel(const float* __restrict__ deg, float* __restrict__ dinv) {
    int i = blockIdx.x * blockDim.x + threadIdx.x;
    if (i >= NNODES) return;
    dinv[i] = rsqrtf(deg[i] + 1.0f);   // deg includes +1 self-loop -> always > 0
}

__global__ void norm_kernel(const int* __restrict__ eidx, const float* __restrict__ w,
                            const float* __restrict__ dinv, float* __restrict__ nrm,
                            const int* __restrict__ flag) {
    int e = blockIdx.x * blockDim.x + threadIdx.x;
    if (e >= NEDGES) return;
    int stride = *flag;
    int row = eidx[(long long)e * (long long)stride];
    int col = eidx[((long long)NEDGES + e) * (long long)stride];
    nrm[e] = dinv[row] * w[e] * dinv[col];
}

// ---------------------------------------------------------------------------
// y0[n, c] = sum_k x[n,k] * W[c,k]    (W staged in LDS, 40 KB)
__global__ void __launch_bounds__(256) gemm_kernel(const float* __restrict__ x,
                                                   const float* __restrict__ W,
                                                   float* __restrict__ y0) {
    __shared__ float Ws[NCLASS * NFEAT];
    for (int i = threadIdx.x; i < NCLASS * NFEAT; i += blockDim.x) Ws[i] = W[i];
    __syncthreads();
    int row = blockIdx.x * blockDim.x + threadIdx.x;
    if (row >= NNODES) return;
    const float4* xr = (const float4*)(x + (size_t)row * NFEAT);
    float acc[NCLASS];
#pragma unroll
    for (int c = 0; c < NCLASS; c++) acc[c] = 0.f;
    for (int k4 = 0; k4 < NFEAT / 4; k4++) {
        float4 v = xr[k4];
#pragma unroll
        for (int c = 0; c < NCLASS; c++) {
            const float* wc = &Ws[c * NFEAT + k4 * 4];
            acc[c] += v.x * wc[0] + v.y * wc[1] + v.z * wc[2] + v.w * wc[3];
        }
    }
    float* yr = y0 + (size_t)row * NCLASS;
#pragma unroll
    for (int c = 0; c < NCLASS; c++) yr[c] = acc[c];
}

// ---------------------------------------------------------------------------
// y_out[i, f] = dinv[i]^2 * y_in[i, f]   (self-loop term; also the init)
__global__ void init_self_kernel(const float* __restrict__ dinv,
                                 const float* __restrict__ yin,
                                 float* __restrict__ yout) {
    int idx = blockIdx.x * blockDim.x + threadIdx.x;
    if (idx >= NNODES * NCLASS) return;
    int i = idx / NCLASS;
    float s = dinv[i] * dinv[i];
    yout[idx] = s * yin[idx];
}

// ---------------------------------------------------------------------------
// One thread per (edge, class): y_out[col, f] += norm[e] * y_in[row, f]
// Block = 320 threads = 8 edges x 40 classes.
__global__ void __launch_bounds__(320) hop_kernel(const int* __restrict__ eidx,
                                                  const float* __restrict__ nrm,
                                                  const float* __restrict__ yin,
                                                  float* __restrict__ yout,
                                                  const int* __restrict__ flag) {
    int tid = threadIdx.x;
    int le = tid / NCLASS;        // 0..7
    int f = tid - le * NCLASS;    // 0..39
    int e = blockIdx.x * 8 + le;
    if (e >= NEDGES) return;
    int stride = *flag;
    int row = eidx[(long long)e * (long long)stride];
    int col = eidx[((long long)NEDGES + e) * (long long)stride];
    float v = nrm[e] * yin[(size_t)row * NCLASS + f];
    unsafeAtomicAdd(&yout[(size_t)col * NCLASS + f], v);
}

// ---------------------------------------------------------------------------
// In-place log_softmax over rows of 40, plus bias. One wave per row.
__global__ void softmax_kernel(float* __restrict__ out, const float* __restrict__ b) {
    int gtid = blockIdx.x * blockDim.x + threadIdx.x;
    int wid = gtid >> 6;
    int lane = threadIdx.x & 63;
    if (wid >= NNODES) return;
    float* r = out + (size_t)wid * NCLASS;
    float v = (lane < NCLASS) ? r[lane] + b[lane] : -INFINITY;
    float m = v;
#pragma unroll
    for (int o = 32; o; o >>= 1) m = fmaxf(m, __shfl_xor(m, o));
    float e = (lane < NCLASS) ? expf(v - m) : 0.f;
    float s = e;
#pragma unroll
    for (int o = 32; o; o >>= 1) s += __shfl_xor(s, o);
    float res = v - m - logf(s);
    if (lane < NCLASS) r[lane] = res;
}

// ---------------------------------------------------------------------------
extern "C" void kernel_launch(void* const* d_in, const int* in_sizes, int n_in,
                              void* d_out, int out_size, void* d_ws, size_t ws_size,
                              hipStream_t stream) {
    const float* x = (const float*)d_in[0];
    const int* eidx = (const int*)d_in[1];
    const float* ew = (const float*)d_in[2];
    const float* W = (const float*)d_in[3];
    const float* b = (const float*)d_in[4];
    float* out = (float*)d_out;

    char* ws = (char*)d_ws;
    size_t off = 0;
    auto alloc = [&](size_t bytes) -> char* {
        char* p = ws + off;
        off += (bytes + 255) & ~(size_t)255;
        return p;
    };
    int* flag = (int*)alloc(sizeof(int));
    float* deg = (float*)alloc((size_t)NNODES * 4);
    float* dinv = (float*)alloc((size_t)NNODES * 4);
    float* nrm = (float*)alloc((size_t)NEDGES * 4);
    float* y0 = (float*)alloc((size_t)NNODES * NCLASS * 4);
    float* y1 = (float*)alloc((size_t)NNODES * NCLASS * 4);

    hipMemsetAsync(deg, 0, (size_t)NNODES * 4, stream);
    detect_kernel<<<1, 256, 0, stream>>>(eidx, flag);
    deg_kernel<<<(NEDGES + 255) / 256, 256, 0, stream>>>(eidx, ew, deg, flag);
    dinv_kernel<<<(NNODES + 255) / 256, 256, 0, stream>>>(deg, dinv);
    norm_kernel<<<(NEDGES + 255) / 256, 256, 0, stream>>>(eidx, ew, dinv, nrm, flag);
    gemm_kernel<<<(NNODES + 255) / 256, 256, 0, stream>>>(x, W, y0);
    // hop 1: y1 = A y0
    init_self_kernel<<<(NNODES * NCLASS + 255) / 256, 256, 0, stream>>>(dinv, y0, y1);
    hop_kernel<<<(NEDGES + 7) / 8, 320, 0, stream>>>(eidx, nrm, y0, y1, flag);
    // hop 2: out = A y1
    init_self_kernel<<<(NNODES * NCLASS + 255) / 256, 256, 0, stream>>>(dinv, y1, out);
    hop_kernel<<<(NEDGES + 7) / 8, 320, 0, stream>>>(eidx, nrm, y1, out, flag);
    // logits -> log_softmax (in place, + bias)
    softmax_kernel<<<(NNODES + 3) / 4, 256, 0, stream>>>(out, b);
}

// Round 2
// 1045.070 us; speedup vs baseline: 1.3519x; 1.3519x over previous
//
#include <hip/hip_runtime.h>
#include <cmath>

#define NNODES 100000
#define NEDGES 3200000
#define NFEAT 256
#define NCLASS 40
#define SCAN_BLK 1024
#define NSB ((NNODES + SCAN_BLK - 1) / SCAN_BLK)   // 98

// ---------------------------------------------------------------------------
// Detect whether edge_index arrived as int64 (stride 2 in int32 units) or
// int32 (stride 1). int64 values < 2^31 have all-zero high dwords.
__global__ void detect_kernel(const int* __restrict__ eidx, int* __restrict__ flag) {
    __shared__ int odd_nz;
    if (threadIdx.x == 0) odd_nz = 0;
    __syncthreads();
    int local = 0;
    for (int i = threadIdx.x; i < 2048; i += blockDim.x) {
        if (eidx[2 * i + 1] != 0) local = 1;
    }
    if (local) atomicOr(&odd_nz, 1);
    __syncthreads();
    if (threadIdx.x == 0) *flag = odd_nz ? 1 : 2;
}

// ---------------------------------------------------------------------------
// deg[col] += w (float) and cnt[col]++ (int) in one pass.
__global__ void deg_kernel(const int* __restrict__ eidx, const float* __restrict__ w,
                           float* __restrict__ deg, int* __restrict__ cnt,
                           const int* __restrict__ flag) {
    int e = blockIdx.x * blockDim.x + threadIdx.x;
    if (e >= NEDGES) return;
    int stride = *flag;
    int col = eidx[((long long)NEDGES + e) * (long long)stride];
    unsafeAtomicAdd(&deg[col], w[e]);
    atomicAdd(&cnt[col], 1);
}

__global__ void dinv_kernel(const float* __restrict__ deg, float* __restrict__ dinv) {
    int i = blockIdx.x * blockDim.x + threadIdx.x;
    if (i >= NNODES) return;
    dinv[i] = rsqrtf(deg[i] + 1.0f);   // deg includes +1 self-loop -> always > 0
}

// ---------------------------------------------------------------------------
// Exclusive scan of cnt[NNODES] -> rowptr (3 kernels).
__global__ void scan1_kernel(const int* __restrict__ cnt, int* __restrict__ part,
                             int* __restrict__ bsum) {
    __shared__ int tmp[SCAN_BLK];
    int tid = threadIdx.x;
    int i = blockIdx.x * SCAN_BLK + tid;
    int v = (i < NNODES) ? cnt[i] : 0;
    tmp[tid] = v;
    __syncthreads();
    for (int off = 1; off < SCAN_BLK; off <<= 1) {
        int t = 0;
        if (tid >= off) t = tmp[tid - off];
        __syncthreads();
        if (tid >= off) tmp[tid] += t;
        __syncthreads();
    }
    if (i < NNODES) part[i] = tmp[tid] - v;          // exclusive within block
    if (tid == SCAN_BLK - 1) bsum[blockIdx.x] = tmp[tid];
}

__global__ void scan2_kernel(int* __restrict__ bsum) {
    if (threadIdx.x == 0 && blockIdx.x == 0) {
        int acc = 0;
        for (int i = 0; i < NSB; i++) { int t = bsum[i]; bsum[i] = acc; acc += t; }
    }
}

__global__ void scan3_kernel(int* __restrict__ part, const int* __restrict__ bsum,
                             int* __restrict__ rowptr, int* __restrict__ fill) {
    int i = blockIdx.x * blockDim.x + threadIdx.x;
    if (i >= NNODES) return;
    int v = part[i] + bsum[i / SCAN_BLK];
    rowptr[i] = v;
    fill[i] = v;
    if (i == 0) rowptr[NNODES] = NEDGES;
}

// ---------------------------------------------------------------------------
// Scatter edges into CSR (grouped by destination col), norm fused in.
__global__ void scatter_kernel(const int* __restrict__ eidx, const float* __restrict__ ew,
                               const float* __restrict__ dinv, int2* __restrict__ csr,
                               int* __restrict__ fill, const int* __restrict__ flag) {
    int e = blockIdx.x * blockDim.x + threadIdx.x;
    if (e >= NEDGES) return;
    int stride = *flag;
    int row = eidx[(long long)e * (long long)stride];
    int col = eidx[((long long)NEDGES + e) * (long long)stride];
    float nm = dinv[row] * ew[e] * dinv[col];
    int pos = atomicAdd(&fill[col], 1);
    int2 p; p.x = row; p.y = __float_as_int(nm);
    csr[pos] = p;
}

// ---------------------------------------------------------------------------
// y0[n, c] = sum_k x[n,k] * W[c,k]    (W staged in LDS, 40 KB)
__global__ void __launch_bounds__(256) gemm_kernel(const float* __restrict__ x,
                                                   const float* __restrict__ W,
                                                   float* __restrict__ y0) {
    __shared__ float Ws[NCLASS * NFEAT];
    for (int i = threadIdx.x; i < NCLASS * NFEAT; i += blockDim.x) Ws[i] = W[i];
    __syncthreads();
    int row = blockIdx.x * blockDim.x + threadIdx.x;
    if (row >= NNODES) return;
    const float4* xr = (const float4*)(x + (size_t)row * NFEAT);
    float acc[NCLASS];
#pragma unroll
    for (int c = 0; c < NCLASS; c++) acc[c] = 0.f;
    for (int k4 = 0; k4 < NFEAT / 4; k4++) {
        float4 v = xr[k4];
#pragma unroll
        for (int c = 0; c < NCLASS; c++) {
            const float* wc = &Ws[c * NFEAT + k4 * 4];
            acc[c] += v.x * wc[0] + v.y * wc[1] + v.z * wc[2] + v.w * wc[3];
        }
    }
    float* yr = y0 + (size_t)row * NCLASS;
#pragma unroll
    for (int c = 0; c < NCLASS; c++) yr[c] = acc[c];
}

// ---------------------------------------------------------------------------
// Gather hop: thread (n, c) accumulates over incoming edges of node n.
// Block = 320 threads = 8 nodes x 40 classes.
__global__ void __launch_bounds__(320) hop_csr_kernel(const int* __restrict__ rowptr,
                                                      const int2* __restrict__ csr,
                                                      const float* __restrict__ dinv,
                                                      const float* __restrict__ yin,
                                                      float* __restrict__ yout) {
    int tid = threadIdx.x;
    int ln = tid / NCLASS;          // 0..7
    int c = tid - ln * NCLASS;      // 0..39
    int n = blockIdx.x * 8 + ln;
    if (n >= NNODES) return;
    float d = dinv[n];
    float acc = d * d * yin[(size_t)n * NCLASS + c];   // self-loop term
    int e0 = rowptr[n], e1 = rowptr[n + 1];
    for (int e = e0; e < e1; e++) {
        int2 p = csr[e];
        acc += __int_as_float(p.y) * yin[(size_t)p.x * NCLASS + c];
    }
    yout[(size_t)n * NCLASS + c] = acc;
}

// ---------------------------------------------------------------------------
// In-place log_softmax over rows of 40, plus bias. One wave per row.
__global__ void softmax_kernel(float* __restrict__ out, const float* __restrict__ b) {
    int gtid = blockIdx.x * blockDim.x + threadIdx.x;
    int wid = gtid >> 6;
    int lane = threadIdx.x & 63;
    if (wid >= NNODES) return;
    float* r = out + (size_t)wid * NCLASS;
    float v = (lane < NCLASS) ? r[lane] + b[lane] : -INFINITY;
    float m = v;
#pragma unroll
    for (int o = 32; o; o >>= 1) m = fmaxf(m, __shfl_xor(m, o));
    float e = (lane < NCLASS) ? expf(v - m) : 0.f;
    float s = e;
#pragma unroll
    for (int o = 32; o; o >>= 1) s += __shfl_xor(s, o);
    float res = v - m - logf(s);
    if (lane < NCLASS) r[lane] = res;
}

// ---------------------------------------------------------------------------
extern "C" void kernel_launch(void* const* d_in, const int* in_sizes, int n_in,
                              void* d_out, int out_size, void* d_ws, size_t ws_size,
                              hipStream_t stream) {
    const float* x = (const float*)d_in[0];
    const int* eidx = (const int*)d_in[1];
    const float* ew = (const float*)d_in[2];
    const float* W = (const float*)d_in[3];
    const float* b = (const float*)d_in[4];
    float* out = (float*)d_out;

    char* ws = (char*)d_ws;
    size_t off = 0;
    auto alloc = [&](size_t bytes) -> char* {
        char* p = ws + off;
        off += (bytes + 255) & ~(size_t)255;
        return p;
    };
    int* flag = (int*)alloc(sizeof(int));
    float* deg = (float*)alloc((size_t)NNODES * 4);
    float* dinv = (float*)alloc((size_t)NNODES * 4);
    int* cnt = (int*)alloc((size_t)NNODES * 4);
    int* part = (int*)alloc((size_t)NNODES * 4);
    int* bsum = (int*)alloc((size_t)NSB * 4);
    int* rowptr = (int*)alloc((size_t)(NNODES + 1) * 4);
    int* fill = (int*)alloc((size_t)NNODES * 4);
    int2* csr = (int2*)alloc((size_t)NEDGES * 8);
    float* y0 = (float*)alloc((size_t)NNODES * NCLASS * 4);
    float* y1 = (float*)alloc((size_t)NNODES * NCLASS * 4);

    hipMemsetAsync(deg, 0, (size_t)NNODES * 4, stream);
    hipMemsetAsync(cnt, 0, (size_t)NNODES * 4, stream);
    detect_kernel<<<1, 256, 0, stream>>>(eidx, flag);
    deg_kernel<<<(NEDGES + 255) / 256, 256, 0, stream>>>(eidx, ew, deg, cnt, flag);
    dinv_kernel<<<(NNODES + 255) / 256, 256, 0, stream>>>(deg, dinv);
    // exclusive scan cnt -> rowptr, fill
    scan1_kernel<<<NSB, SCAN_BLK, 0, stream>>>(cnt, part, bsum);
    scan2_kernel<<<1, 64, 0, stream>>>(bsum);
    scan3_kernel<<<(NNODES + 255) / 256, 256, 0, stream>>>(part, bsum, rowptr, fill);
    // scatter edges into CSR grouped by col (norm fused)
    scatter_kernel<<<(NEDGES + 255) / 256, 256, 0, stream>>>(eidx, ew, dinv, csr, fill, flag);
    // project features first: y0 = x @ W.T  (propagation and projection commute)
    gemm_kernel<<<(NNODES + 255) / 256, 256, 0, stream>>>(x, W, y0);
    // hop 1: y1 = A y0 ; hop 2: out = A y1 (gather form, no float atomics)
    hop_csr_kernel<<<(NNODES + 7) / 8, 320, 0, stream>>>(rowptr, csr, dinv, y0, y1);
    hop_csr_kernel<<<(NNODES + 7) / 8, 320, 0, stream>>>(rowptr, csr, dinv, y1, out);
    // logits -> log_softmax (in place, + bias)
    softmax_kernel<<<(NNODES + 3) / 4, 256, 0, stream>>>(out, b);
}

// Round 3
// 698.165 us; speedup vs baseline: 2.0236x; 1.4969x over previous
//
#include <hip/hip_runtime.h>
#include <cmath>

#define NNODES 100000
#define NEDGES 3200000
#define NFEAT 256
#define NCLASS 40

#define BSHIFT 8
#define BSIZE 256                                  // nodes per coarse bucket
#define NBUCK ((NNODES + BSIZE - 1) / BSIZE)       // 391
#define ECHUNK 16384
#define NCB ((NEDGES + ECHUNK - 1) / ECHUNK)       // 196

// ---------------------------------------------------------------------------
// Detect whether edge_index arrived as int64 (stride 2 in int32 units) or
// int32 (stride 1). int64 values < 2^31 have all-zero high dwords.
__global__ void detect_kernel(const int* __restrict__ eidx, int* __restrict__ flag) {
    __shared__ int odd_nz;
    if (threadIdx.x == 0) odd_nz = 0;
    __syncthreads();
    int local = 0;
    for (int i = threadIdx.x; i < 2048; i += blockDim.x) {
        if (eidx[2 * i + 1] != 0) local = 1;
    }
    if (local) atomicOr(&odd_nz, 1);
    __syncthreads();
    if (threadIdx.x == 0) *flag = odd_nz ? 1 : 2;
}

// ---------------------------------------------------------------------------
// Coarse histogram of col>>BSHIFT (LDS per block, then global add).
__global__ void __launch_bounds__(256) chist_kernel(const int* __restrict__ eidx,
                                                    int* __restrict__ ghist,
                                                    const int* __restrict__ flag) {
    __shared__ int h[NBUCK];
    for (int i = threadIdx.x; i < NBUCK; i += 256) h[i] = 0;
    __syncthreads();
    int stride = *flag;
    long long cb = (long long)NEDGES * stride;
    int e0 = blockIdx.x * ECHUNK;
    int e1 = min(e0 + ECHUNK, NEDGES);
    for (int e = e0 + threadIdx.x; e < e1; e += 256) {
        int col = eidx[cb + (long long)e * stride];
        atomicAdd(&h[col >> BSHIFT], 1);
    }
    __syncthreads();
    for (int i = threadIdx.x; i < NBUCK; i += 256)
        if (h[i]) atomicAdd(&ghist[i], h[i]);
}

// ---------------------------------------------------------------------------
// One-block scan of the 391 coarse counts -> cbase[392] and cursor[391].
__global__ void __launch_bounds__(512) cscan_kernel(const int* __restrict__ ghist,
                                                    int* __restrict__ cbase,
                                                    int* __restrict__ cursor) {
    __shared__ int bufa[512], bufb[512];
    int t = threadIdx.x;
    bufa[t] = (t < NBUCK) ? ghist[t] : 0;
    __syncthreads();
    int* s = bufa; int* d = bufb;
    for (int off = 1; off < 512; off <<= 1) {
        d[t] = s[t] + ((t >= off) ? s[t - off] : 0);
        __syncthreads();
        int* tmp = s; s = d; d = tmp;
    }
    int excl = (t == 0) ? 0 : s[t - 1];
    if (t < NBUCK) { cbase[t] = excl; cursor[t] = excl; }
    if (t == NBUCK) cbase[t] = excl;
}

// ---------------------------------------------------------------------------
// Coarse scatter: group edges by col>>BSHIFT. Packed entry:
//   .x = (src << BSHIFT) | (col & (BSIZE-1))   (17+8 bits < 32)
//   .y = float bits of edge weight
__global__ void __launch_bounds__(256) cscatter_kernel(const int* __restrict__ eidx,
                                                       const float* __restrict__ ew,
                                                       int2* __restrict__ coarse,
                                                       int* __restrict__ cursor,
                                                       const int* __restrict__ flag) {
    __shared__ int h[NBUCK];
    __shared__ int lbase[NBUCK];
    for (int i = threadIdx.x; i < NBUCK; i += 256) h[i] = 0;
    __syncthreads();
    int stride = *flag;
    long long cb = (long long)NEDGES * stride;
    int e0 = blockIdx.x * ECHUNK;
    int e1 = min(e0 + ECHUNK, NEDGES);
    for (int e = e0 + threadIdx.x; e < e1; e += 256) {
        int col = eidx[cb + (long long)e * stride];
        atomicAdd(&h[col >> BSHIFT], 1);
    }
    __syncthreads();
    for (int i = threadIdx.x; i < NBUCK; i += 256) {
        int c = h[i];
        lbase[i] = c ? atomicAdd(&cursor[i], c) : 0;
        h[i] = 0;                      // reuse as local cursor
    }
    __syncthreads();
    for (int e = e0 + threadIdx.x; e < e1; e += 256) {
        int col = eidx[cb + (long long)e * stride];
        int src = eidx[(long long)e * stride];
        float w = ew[e];
        int bk = col >> BSHIFT;
        int pos = lbase[bk] + atomicAdd(&h[bk], 1);
        coarse[pos] = make_int2((src << BSHIFT) | (col & (BSIZE - 1)), __float_as_int(w));
    }
}

// ---------------------------------------------------------------------------
// Fine pass: one block per coarse bucket. Groups edges by exact col (LDS),
// computes weighted degree -> dinv (written globally), writes rowptr and
// CSR entries (src, w * dinv[col]).
__global__ void __launch_bounds__(256) fine_kernel(const int2* __restrict__ coarse,
                                                   const int* __restrict__ cbase,
                                                   int* __restrict__ rowptr,
                                                   float* __restrict__ dinv,
                                                   int2* __restrict__ csr) {
    __shared__ int hist[BSIZE];
    __shared__ float wdeg[BSIZE];
    __shared__ int foff[BSIZE];
    __shared__ int sa[BSIZE], sb[BSIZE];
    int t = threadIdx.x;
    int bk = blockIdx.x;
    hist[t] = 0;
    wdeg[t] = 0.f;
    __syncthreads();
    int eb = cbase[bk], ee = cbase[bk + 1];
    for (int i = eb + t; i < ee; i += 256) {
        int2 v = coarse[i];
        int loc = v.x & (BSIZE - 1);
        atomicAdd(&hist[loc], 1);
        atomicAdd(&wdeg[loc], __int_as_float(v.y));
    }
    __syncthreads();
    // dinv for this bucket's columns (deg + 1 self-loop)
    int gcol = (bk << BSHIFT) + t;
    float dv = rsqrtf(wdeg[t] + 1.0f);
    wdeg[t] = dv;                                  // now holds dinv[col]
    if (gcol < NNODES) dinv[gcol] = dv;
    // exclusive scan of hist -> foff
    sa[t] = hist[t];
    __syncthreads();
    int* s = sa; int* d = sb;
    for (int off = 1; off < BSIZE; off <<= 1) {
        d[t] = s[t] + ((t >= off) ? s[t - off] : 0);
        __syncthreads();
        int* tmp = s; s = d; d = tmp;
    }
    foff[t] = (t == 0) ? 0 : s[t - 1];
    hist[t] = 0;                                   // reuse as fine cursor
    __syncthreads();
    if (gcol <= NNODES) rowptr[gcol] = eb + foff[t];   // gcol==NNODES -> NEDGES
    for (int i = eb + t; i < ee; i += 256) {
        int2 v = coarse[i];
        int loc = v.x & (BSIZE - 1);
        int srcn = ((unsigned)v.x) >> BSHIFT;
        int pos = eb + foff[loc] + atomicAdd(&hist[loc], 1);
        csr[pos] = make_int2(srcn, __float_as_int(__int_as_float(v.y) * wdeg[loc]));
    }
}

// ---------------------------------------------------------------------------
// csr[e].y *= dinv[src]  (completes norm = dinv[src]*w*dinv[col])
__global__ void __launch_bounds__(256) fixup_kernel(int2* __restrict__ csr,
                                                    const float* __restrict__ dinv) {
    int e = blockIdx.x * 256 + threadIdx.x;
    if (e >= NEDGES) return;
    int2 v = csr[e];
    v.y = __float_as_int(__int_as_float(v.y) * dinv[v.x]);
    csr[e] = v;
}

// ---------------------------------------------------------------------------
// y0[n, c] = sum_k x[n,k] * W[c,k]    (W staged in LDS, 40 KB)
__global__ void __launch_bounds__(256) gemm_kernel(const float* __restrict__ x,
                                                   const float* __restrict__ W,
                                                   float* __restrict__ y0) {
    __shared__ float Ws[NCLASS * NFEAT];
    for (int i = threadIdx.x; i < NCLASS * NFEAT; i += blockDim.x) Ws[i] = W[i];
    __syncthreads();
    int row = blockIdx.x * blockDim.x + threadIdx.x;
    if (row >= NNODES) return;
    const float4* xr = (const float4*)(x + (size_t)row * NFEAT);
    float acc[NCLASS];
#pragma unroll
    for (int c = 0; c < NCLASS; c++) acc[c] = 0.f;
    for (int k4 = 0; k4 < NFEAT / 4; k4++) {
        float4 v = xr[k4];
#pragma unroll
        for (int c = 0; c < NCLASS; c++) {
            const float* wc = &Ws[c * NFEAT + k4 * 4];
            acc[c] += v.x * wc[0] + v.y * wc[1] + v.z * wc[2] + v.w * wc[3];
        }
    }
    float* yr = y0 + (size_t)row * NCLASS;
#pragma unroll
    for (int c = 0; c < NCLASS; c++) yr[c] = acc[c];
}

// ---------------------------------------------------------------------------
// Gather hop: thread (n, c) accumulates over incoming edges of node n.
// Block = 320 threads = 8 nodes x 40 classes.
__global__ void __launch_bounds__(320) hop_csr_kernel(const int* __restrict__ rowptr,
                                                      const int2* __restrict__ csr,
                                                      const float* __restrict__ dinv,
                                                      const float* __restrict__ yin,
                                                      float* __restrict__ yout) {
    int tid = threadIdx.x;
    int ln = tid / NCLASS;          // 0..7
    int c = tid - ln * NCLASS;      // 0..39
    int n = blockIdx.x * 8 + ln;
    if (n >= NNODES) return;
    float d = dinv[n];
    float acc = d * d * yin[(size_t)n * NCLASS + c];   // self-loop term
    int e0 = rowptr[n], e1 = rowptr[n + 1];
    for (int e = e0; e < e1; e++) {
        int2 p = csr[e];
        acc += __int_as_float(p.y) * yin[(size_t)p.x * NCLASS + c];
    }
    yout[(size_t)n * NCLASS + c] = acc;
}

// ---------------------------------------------------------------------------
// In-place log_softmax over rows of 40, plus bias. One wave per row.
__global__ void softmax_kernel(float* __restrict__ out, const float* __restrict__ b) {
    int gtid = blockIdx.x * blockDim.x + threadIdx.x;
    int wid = gtid >> 6;
    int lane = threadIdx.x & 63;
    if (wid >= NNODES) return;
    float* r = out + (size_t)wid * NCLASS;
    float v = (lane < NCLASS) ? r[lane] + b[lane] : -INFINITY;
    float m = v;
#pragma unroll
    for (int o = 32; o; o >>= 1) m = fmaxf(m, __shfl_xor(m, o));
    float e = (lane < NCLASS) ? expf(v - m) : 0.f;
    float s = e;
#pragma unroll
    for (int o = 32; o; o >>= 1) s += __shfl_xor(s, o);
    float res = v - m - logf(s);
    if (lane < NCLASS) r[lane] = res;
}

// ---------------------------------------------------------------------------
extern "C" void kernel_launch(void* const* d_in, const int* in_sizes, int n_in,
                              void* d_out, int out_size, void* d_ws, size_t ws_size,
                              hipStream_t stream) {
    const float* x = (const float*)d_in[0];
    const int* eidx = (const int*)d_in[1];
    const float* ew = (const float*)d_in[2];
    const float* W = (const float*)d_in[3];
    const float* b = (const float*)d_in[4];
    float* out = (float*)d_out;

    char* ws = (char*)d_ws;
    size_t off = 0;
    auto alloc = [&](size_t bytes) -> char* {
        char* p = ws + off;
        off += (bytes + 255) & ~(size_t)255;
        return p;
    };
    int* flag = (int*)alloc(sizeof(int));
    int* ghist = (int*)alloc((size_t)NBUCK * 4);
    int* cbase = (int*)alloc((size_t)(NBUCK + 1) * 4);
    int* cursor = (int*)alloc((size_t)NBUCK * 4);
    int* rowptr = (int*)alloc((size_t)(NNODES + 1) * 4);
    float* dinv = (float*)alloc((size_t)NNODES * 4);
    int2* csr = (int2*)alloc((size_t)NEDGES * 8);
    // coarse buffer aliases y0/y1: coarse (25.6 MB) is fully consumed by
    // fine_kernel before gemm writes y0 (16 MB) / hop writes y1 (16 MB).
    char* un = alloc((size_t)NNODES * NCLASS * 4 * 2);
    int2* coarse = (int2*)un;
    float* y0 = (float*)un;
    float* y1 = (float*)(un + (size_t)NNODES * NCLASS * 4);

    hipMemsetAsync(ghist, 0, (size_t)NBUCK * 4, stream);
    detect_kernel<<<1, 256, 0, stream>>>(eidx, flag);
    chist_kernel<<<NCB, 256, 0, stream>>>(eidx, ghist, flag);
    cscan_kernel<<<1, 512, 0, stream>>>(ghist, cbase, cursor);
    cscatter_kernel<<<NCB, 256, 0, stream>>>(eidx, ew, coarse, cursor, flag);
    fine_kernel<<<NBUCK, 256, 0, stream>>>(coarse, cbase, rowptr, dinv, csr);
    fixup_kernel<<<(NEDGES + 255) / 256, 256, 0, stream>>>(csr, dinv);
    // project features first: y0 = x @ W.T  (propagation and projection commute)
    gemm_kernel<<<(NNODES + 255) / 256, 256, 0, stream>>>(x, W, y0);
    // hop 1: y1 = A y0 ; hop 2: out = A y1 (gather form, no float atomics)
    hop_csr_kernel<<<(NNODES + 7) / 8, 320, 0, stream>>>(rowptr, csr, dinv, y0, y1);
    hop_csr_kernel<<<(NNODES + 7) / 8, 320, 0, stream>>>(rowptr, csr, dinv, y1, out);
    // logits -> log_softmax (in place, + bias)
    softmax_kernel<<<(NNODES + 3) / 4, 256, 0, stream>>>(out, b);
}

// Round 4
// 340.470 us; speedup vs baseline: 4.1496x; 2.0506x over previous
//
#include <hip/hip_runtime.h>
#include <hip/hip_fp16.h>
#include <cmath>

#define NNODES 100000
#define NEDGES 3200000
#define NFEAT 256
#define NCLASS 40

#define BSHIFT 8
#define BSIZE 256                                  // nodes per coarse bucket
#define NBUCK ((NNODES + BSIZE - 1) / BSIZE)       // 391
#define ECHUNK 16384
#define NCB ((NEDGES + ECHUNK - 1) / ECHUNK)       // 196

// fp16 intermediate rows: 64 halves (128 B, one cache line), classes in 0..39
#define ROWU2 16                                   // uint2 (4 halves) per row

__device__ inline unsigned pk2(float a, float b) {
    __half2 h;
    h.x = __float2half_rn(a);
    h.y = __float2half_rn(b);
    return *reinterpret_cast<unsigned*>(&h);
}
__device__ inline float2 up2(unsigned u) {
    __half2 h = *reinterpret_cast<__half2*>(&u);
    float2 f;
    f.x = __half2float(h.x);
    f.y = __half2float(h.y);
    return f;
}

// ---------------------------------------------------------------------------
// Detect whether edge_index arrived as int64 (stride 2 in int32 units) or
// int32 (stride 1). int64 values < 2^31 have all-zero high dwords.
__global__ void detect_kernel(const int* __restrict__ eidx, int* __restrict__ flag) {
    __shared__ int odd_nz;
    if (threadIdx.x == 0) odd_nz = 0;
    __syncthreads();
    int local = 0;
    for (int i = threadIdx.x; i < 2048; i += blockDim.x) {
        if (eidx[2 * i + 1] != 0) local = 1;
    }
    if (local) atomicOr(&odd_nz, 1);
    __syncthreads();
    if (threadIdx.x == 0) *flag = odd_nz ? 1 : 2;
}

// ---------------------------------------------------------------------------
// Coarse histogram of col>>BSHIFT (LDS per block, then global add).
__global__ void __launch_bounds__(256) chist_kernel(const int* __restrict__ eidx,
                                                    int* __restrict__ ghist,
                                                    const int* __restrict__ flag) {
    __shared__ int h[NBUCK];
    for (int i = threadIdx.x; i < NBUCK; i += 256) h[i] = 0;
    __syncthreads();
    int stride = *flag;
    long long cb = (long long)NEDGES * stride;
    int e0 = blockIdx.x * ECHUNK;
    int e1 = min(e0 + ECHUNK, NEDGES);
    for (int e = e0 + threadIdx.x; e < e1; e += 256) {
        int col = eidx[cb + (long long)e * stride];
        atomicAdd(&h[col >> BSHIFT], 1);
    }
    __syncthreads();
    for (int i = threadIdx.x; i < NBUCK; i += 256)
        if (h[i]) atomicAdd(&ghist[i], h[i]);
}

// ---------------------------------------------------------------------------
// One-block scan of the 391 coarse counts -> cbase[392] and cursor[391].
__global__ void __launch_bounds__(512) cscan_kernel(const int* __restrict__ ghist,
                                                    int* __restrict__ cbase,
                                                    int* __restrict__ cursor) {
    __shared__ int bufa[512], bufb[512];
    int t = threadIdx.x;
    bufa[t] = (t < NBUCK) ? ghist[t] : 0;
    __syncthreads();
    int* s = bufa; int* d = bufb;
    for (int off = 1; off < 512; off <<= 1) {
        d[t] = s[t] + ((t >= off) ? s[t - off] : 0);
        __syncthreads();
        int* tmp = s; s = d; d = tmp;
    }
    int excl = (t == 0) ? 0 : s[t - 1];
    if (t < NBUCK) { cbase[t] = excl; cursor[t] = excl; }
    if (t == NBUCK) cbase[t] = excl;
}

// ---------------------------------------------------------------------------
// Coarse scatter: group edges by col>>BSHIFT. Packed entry:
//   .x = (src << BSHIFT) | (col & (BSIZE-1))   (17+8 bits < 32)
//   .y = float bits of edge weight
__global__ void __launch_bounds__(256) cscatter_kernel(const int* __restrict__ eidx,
                                                       const float* __restrict__ ew,
                                                       int2* __restrict__ coarse,
                                                       int* __restrict__ cursor,
                                                       const int* __restrict__ flag) {
    __shared__ int h[NBUCK];
    __shared__ int lbase[NBUCK];
    for (int i = threadIdx.x; i < NBUCK; i += 256) h[i] = 0;
    __syncthreads();
    int stride = *flag;
    long long cb = (long long)NEDGES * stride;
    int e0 = blockIdx.x * ECHUNK;
    int e1 = min(e0 + ECHUNK, NEDGES);
    for (int e = e0 + threadIdx.x; e < e1; e += 256) {
        int col = eidx[cb + (long long)e * stride];
        atomicAdd(&h[col >> BSHIFT], 1);
    }
    __syncthreads();
    for (int i = threadIdx.x; i < NBUCK; i += 256) {
        int c = h[i];
        lbase[i] = c ? atomicAdd(&cursor[i], c) : 0;
        h[i] = 0;                      // reuse as local cursor
    }
    __syncthreads();
    for (int e = e0 + threadIdx.x; e < e1; e += 256) {
        int col = eidx[cb + (long long)e * stride];
        int src = eidx[(long long)e * stride];
        float w = ew[e];
        int bk = col >> BSHIFT;
        int pos = lbase[bk] + atomicAdd(&h[bk], 1);
        coarse[pos] = make_int2((src << BSHIFT) | (col & (BSIZE - 1)), __float_as_int(w));
    }
}

// ---------------------------------------------------------------------------
// Fine pass: one block per coarse bucket. Groups edges by exact col (LDS),
// computes weighted degree -> dinv (written globally), writes rowptr and
// CSR entries (src, w * dinv[col]).
__global__ void __launch_bounds__(256) fine_kernel(const int2* __restrict__ coarse,
                                                   const int* __restrict__ cbase,
                                                   int* __restrict__ rowptr,
                                                   float* __restrict__ dinv,
                                                   int2* __restrict__ csr) {
    __shared__ int hist[BSIZE];
    __shared__ float wdeg[BSIZE];
    __shared__ int foff[BSIZE];
    __shared__ int sa[BSIZE], sb[BSIZE];
    int t = threadIdx.x;
    int bk = blockIdx.x;
    hist[t] = 0;
    wdeg[t] = 0.f;
    __syncthreads();
    int eb = cbase[bk], ee = cbase[bk + 1];
    for (int i = eb + t; i < ee; i += 256) {
        int2 v = coarse[i];
        int loc = v.x & (BSIZE - 1);
        atomicAdd(&hist[loc], 1);
        atomicAdd(&wdeg[loc], __int_as_float(v.y));
    }
    __syncthreads();
    // dinv for this bucket's columns (deg + 1 self-loop)
    int gcol = (bk << BSHIFT) + t;
    float dv = rsqrtf(wdeg[t] + 1.0f);
    wdeg[t] = dv;                                  // now holds dinv[col]
    if (gcol < NNODES) dinv[gcol] = dv;
    // exclusive scan of hist -> foff
    sa[t] = hist[t];
    __syncthreads();
    int* s = sa; int* d = sb;
    for (int off = 1; off < BSIZE; off <<= 1) {
        d[t] = s[t] + ((t >= off) ? s[t - off] : 0);
        __syncthreads();
        int* tmp = s; s = d; d = tmp;
    }
    foff[t] = (t == 0) ? 0 : s[t - 1];
    hist[t] = 0;                                   // reuse as fine cursor
    __syncthreads();
    if (gcol <= NNODES) rowptr[gcol] = eb + foff[t];   // gcol==NNODES -> NEDGES
    for (int i = eb + t; i < ee; i += 256) {
        int2 v = coarse[i];
        int loc = v.x & (BSIZE - 1);
        int srcn = ((unsigned)v.x) >> BSHIFT;
        int pos = eb + foff[loc] + atomicAdd(&hist[loc], 1);
        csr[pos] = make_int2(srcn, __float_as_int(__int_as_float(v.y) * wdeg[loc]));
    }
}

// ---------------------------------------------------------------------------
// csr[e].y *= dinv[src]  (completes norm = dinv[src]*w*dinv[col])
__global__ void __launch_bounds__(256) fixup_kernel(int2* __restrict__ csr,
                                                    const float* __restrict__ dinv) {
    int e = blockIdx.x * 256 + threadIdx.x;
    if (e >= NEDGES) return;
    int2 v = csr[e];
    v.y = __float_as_int(__int_as_float(v.y) * dinv[v.x]);
    csr[e] = v;
}

// ---------------------------------------------------------------------------
// y0h[n, :] = fp16(sum_k x[n,k] * W[:,k]), rows padded to 64 halves (128 B).
__global__ void __launch_bounds__(256) gemm_kernel(const float* __restrict__ x,
                                                   const float* __restrict__ W,
                                                   uint2* __restrict__ y0h) {
    __shared__ float Ws[NCLASS * NFEAT];
    for (int i = threadIdx.x; i < NCLASS * NFEAT; i += blockDim.x) Ws[i] = W[i];
    __syncthreads();
    int row = blockIdx.x * blockDim.x + threadIdx.x;
    if (row >= NNODES) return;
    const float4* xr = (const float4*)(x + (size_t)row * NFEAT);
    float acc[NCLASS];
#pragma unroll
    for (int c = 0; c < NCLASS; c++) acc[c] = 0.f;
    for (int k4 = 0; k4 < NFEAT / 4; k4++) {
        float4 v = xr[k4];
#pragma unroll
        for (int c = 0; c < NCLASS; c++) {
            const float* wc = &Ws[c * NFEAT + k4 * 4];
            acc[c] += v.x * wc[0] + v.y * wc[1] + v.z * wc[2] + v.w * wc[3];
        }
    }
    uint2* yr = y0h + (size_t)row * ROWU2;
#pragma unroll
    for (int c4 = 0; c4 < 10; c4++)
        yr[c4] = make_uint2(pk2(acc[4 * c4], acc[4 * c4 + 1]),
                            pk2(acc[4 * c4 + 2], acc[4 * c4 + 3]));
}

// ---------------------------------------------------------------------------
// Hop (fp16 in / fp16 out): thread = (node, 4 classes). 32 nodes x 10 lanes.
// Edge loop unrolled 4x so 4 gathers are in flight per iteration.
__global__ void __launch_bounds__(320) hop16_kernel(const int* __restrict__ rowptr,
                                                    const int2* __restrict__ csr,
                                                    const float* __restrict__ dinv,
                                                    const uint2* __restrict__ yin,
                                                    uint2* __restrict__ yout) {
    int tid = threadIdx.x;
    int ln = tid / 10;
    int c4 = tid - ln * 10;
    int n = blockIdx.x * 32 + ln;
    float d = dinv[n];
    float dd = d * d;
    uint2 sv = yin[(size_t)n * ROWU2 + c4];
    float2 s01 = up2(sv.x), s23 = up2(sv.y);
    float a0 = dd * s01.x, a1 = dd * s01.y, a2 = dd * s23.x, a3 = dd * s23.y;
    int e0 = rowptr[n], e1 = rowptr[n + 1];
    int e = e0;
    for (; e + 4 <= e1; e += 4) {
        int2 p0 = csr[e], p1 = csr[e + 1], p2 = csr[e + 2], p3 = csr[e + 3];
        uint2 g0 = yin[(size_t)p0.x * ROWU2 + c4];
        uint2 g1 = yin[(size_t)p1.x * ROWU2 + c4];
        uint2 g2 = yin[(size_t)p2.x * ROWU2 + c4];
        uint2 g3 = yin[(size_t)p3.x * ROWU2 + c4];
        float w0 = __int_as_float(p0.y), w1 = __int_as_float(p1.y);
        float w2 = __int_as_float(p2.y), w3 = __int_as_float(p3.y);
        { float2 u = up2(g0.x), v = up2(g0.y); a0 += w0 * u.x; a1 += w0 * u.y; a2 += w0 * v.x; a3 += w0 * v.y; }
        { float2 u = up2(g1.x), v = up2(g1.y); a0 += w1 * u.x; a1 += w1 * u.y; a2 += w1 * v.x; a3 += w1 * v.y; }
        { float2 u = up2(g2.x), v = up2(g2.y); a0 += w2 * u.x; a1 += w2 * u.y; a2 += w2 * v.x; a3 += w2 * v.y; }
        { float2 u = up2(g3.x), v = up2(g3.y); a0 += w3 * u.x; a1 += w3 * u.y; a2 += w3 * v.x; a3 += w3 * v.y; }
    }
    for (; e < e1; e++) {
        int2 p = csr[e];
        uint2 g = yin[(size_t)p.x * ROWU2 + c4];
        float w = __int_as_float(p.y);
        float2 u = up2(g.x), v = up2(g.y);
        a0 += w * u.x; a1 += w * u.y; a2 += w * v.x; a3 += w * v.y;
    }
    yout[(size_t)n * ROWU2 + c4] = make_uint2(pk2(a0, a1), pk2(a2, a3));
}

// ---------------------------------------------------------------------------
// Final hop (fp16 in / f32 out) with bias + log_softmax fused.
__global__ void __launch_bounds__(320) hop32_kernel(const int* __restrict__ rowptr,
                                                    const int2* __restrict__ csr,
                                                    const float* __restrict__ dinv,
                                                    const uint2* __restrict__ yin,
                                                    const float* __restrict__ bias,
                                                    float* __restrict__ out) {
    __shared__ float redm[32][10];
    __shared__ float reds[32][10];
    int tid = threadIdx.x;
    int ln = tid / 10;
    int c4 = tid - ln * 10;
    int n = blockIdx.x * 32 + ln;          // NNODES == 3125*32, no tail
    float d = dinv[n];
    float dd = d * d;
    uint2 sv = yin[(size_t)n * ROWU2 + c4];
    float2 s01 = up2(sv.x), s23 = up2(sv.y);
    float a0 = dd * s01.x, a1 = dd * s01.y, a2 = dd * s23.x, a3 = dd * s23.y;
    int e0 = rowptr[n], e1 = rowptr[n + 1];
    int e = e0;
    for (; e + 4 <= e1; e += 4) {
        int2 p0 = csr[e], p1 = csr[e + 1], p2 = csr[e + 2], p3 = csr[e + 3];
        uint2 g0 = yin[(size_t)p0.x * ROWU2 + c4];
        uint2 g1 = yin[(size_t)p1.x * ROWU2 + c4];
        uint2 g2 = yin[(size_t)p2.x * ROWU2 + c4];
        uint2 g3 = yin[(size_t)p3.x * ROWU2 + c4];
        float w0 = __int_as_float(p0.y), w1 = __int_as_float(p1.y);
        float w2 = __int_as_float(p2.y), w3 = __int_as_float(p3.y);
        { float2 u = up2(g0.x), v = up2(g0.y); a0 += w0 * u.x; a1 += w0 * u.y; a2 += w0 * v.x; a3 += w0 * v.y; }
        { float2 u = up2(g1.x), v = up2(g1.y); a0 += w1 * u.x; a1 += w1 * u.y; a2 += w1 * v.x; a3 += w1 * v.y; }
        { float2 u = up2(g2.x), v = up2(g2.y); a0 += w2 * u.x; a1 += w2 * u.y; a2 += w2 * v.x; a3 += w2 * v.y; }
        { float2 u = up2(g3.x), v = up2(g3.y); a0 += w3 * u.x; a1 += w3 * u.y; a2 += w3 * v.x; a3 += w3 * v.y; }
    }
    for (; e < e1; e++) {
        int2 p = csr[e];
        uint2 g = yin[(size_t)p.x * ROWU2 + c4];
        float w = __int_as_float(p.y);
        float2 u = up2(g.x), v = up2(g.y);
        a0 += w * u.x; a1 += w * u.y; a2 += w * v.x; a3 += w * v.y;
    }
    // + bias
    float4 bb = *(const float4*)(bias + c4 * 4);
    float v0 = a0 + bb.x, v1 = a1 + bb.y, v2 = a2 + bb.z, v3 = a3 + bb.w;
    // log_softmax over the node's 40 classes (10 lanes x 4)
    redm[ln][c4] = fmaxf(fmaxf(v0, v1), fmaxf(v2, v3));
    __syncthreads();
    if (c4 == 0) {
        float m = redm[ln][0];
#pragma unroll
        for (int j = 1; j < 10; j++) m = fmaxf(m, redm[ln][j]);
        redm[ln][0] = m;
    }
    __syncthreads();
    float m = redm[ln][0];
    reds[ln][c4] = __expf(v0 - m) + __expf(v1 - m) + __expf(v2 - m) + __expf(v3 - m);
    __syncthreads();
    if (c4 == 0) {
        float s = 0.f;
#pragma unroll
        for (int j = 0; j < 10; j++) s += reds[ln][j];
        reds[ln][0] = logf(s);
    }
    __syncthreads();
    float ls = reds[ln][0];
    float4 r = make_float4(v0 - m - ls, v1 - m - ls, v2 - m - ls, v3 - m - ls);
    *(float4*)(out + (size_t)n * NCLASS + c4 * 4) = r;
}

// ---------------------------------------------------------------------------
extern "C" void kernel_launch(void* const* d_in, const int* in_sizes, int n_in,
                              void* d_out, int out_size, void* d_ws, size_t ws_size,
                              hipStream_t stream) {
    const float* x = (const float*)d_in[0];
    const int* eidx = (const int*)d_in[1];
    const float* ew = (const float*)d_in[2];
    const float* W = (const float*)d_in[3];
    const float* b = (const float*)d_in[4];
    float* out = (float*)d_out;

    char* ws = (char*)d_ws;
    size_t off = 0;
    auto alloc = [&](size_t bytes) -> char* {
        char* p = ws + off;
        off += (bytes + 255) & ~(size_t)255;
        return p;
    };
    int* flag = (int*)alloc(sizeof(int));
    int* ghist = (int*)alloc((size_t)NBUCK * 4);
    int* cbase = (int*)alloc((size_t)(NBUCK + 1) * 4);
    int* cursor = (int*)alloc((size_t)NBUCK * 4);
    int* rowptr = (int*)alloc((size_t)(NNODES + 1) * 4);
    float* dinv = (float*)alloc((size_t)NNODES * 4);
    int2* csr = (int2*)alloc((size_t)NEDGES * 8);
    // coarse buffer (25.6 MB) aliases y0h+y1h (12.8 MB each): coarse is fully
    // consumed by fine_kernel before gemm writes y0h.
    char* un = alloc((size_t)NNODES * 128 * 2);
    int2* coarse = (int2*)un;
    uint2* y0h = (uint2*)un;
    uint2* y1h = (uint2*)(un + (size_t)NNODES * 128);

    hipMemsetAsync(ghist, 0, (size_t)NBUCK * 4, stream);
    detect_kernel<<<1, 256, 0, stream>>>(eidx, flag);
    chist_kernel<<<NCB, 256, 0, stream>>>(eidx, ghist, flag);
    cscan_kernel<<<1, 512, 0, stream>>>(ghist, cbase, cursor);
    cscatter_kernel<<<NCB, 256, 0, stream>>>(eidx, ew, coarse, cursor, flag);
    fine_kernel<<<NBUCK, 256, 0, stream>>>(coarse, cbase, rowptr, dinv, csr);
    fixup_kernel<<<(NEDGES + 255) / 256, 256, 0, stream>>>(csr, dinv);
    // project features first: y0 = x @ W.T  (propagation and projection commute)
    gemm_kernel<<<(NNODES + 255) / 256, 256, 0, stream>>>(x, W, y0h);
    // hop 1: y1 = A y0 (fp16 storage); hop 2: out = log_softmax(A y1 + b)
    hop16_kernel<<<NNODES / 32, 320, 0, stream>>>(rowptr, csr, dinv, y0h, y1h);
    hop32_kernel<<<NNODES / 32, 320, 0, stream>>>(rowptr, csr, dinv, y1h, b, out);
}

// Round 5
// 288.068 us; speedup vs baseline: 4.9045x; 1.1819x over previous
//
#include <hip/hip_runtime.h>
#include <hip/hip_fp16.h>
#include <cmath>

#define NNODES 100000
#define NEDGES 3200000
#define NFEAT 256
#define NCLASS 40

#define BSHIFT 8
#define BSIZE 256                                  // nodes per coarse bucket
#define NBUCK ((NNODES + BSIZE - 1) / BSIZE)       // 391
#define ECHUNK 16384
#define NCB ((NEDGES + ECHUNK - 1) / ECHUNK)       // 196

// fp16 intermediate rows: 64 halves (128 B, one cache line), classes in 0..39
#define ROWU2 16                                   // uint2 (4 halves) per row

using bf16x8 = __attribute__((ext_vector_type(8))) short;
using f32x4 = __attribute__((ext_vector_type(4))) float;

__device__ inline unsigned pk2(float a, float b) {
    __half2 h;
    h.x = __float2half_rn(a);
    h.y = __float2half_rn(b);
    return *reinterpret_cast<unsigned*>(&h);
}
__device__ inline float2 up2(unsigned u) {
    __half2 h = *reinterpret_cast<__half2*>(&u);
    float2 f;
    f.x = __half2float(h.x);
    f.y = __half2float(h.y);
    return f;
}
__device__ inline unsigned short f2bf(float f) {   // f32 -> bf16, round-nearest-even
    unsigned u = __float_as_uint(f);
    unsigned r = (u + 0x7FFFu + ((u >> 16) & 1u)) >> 16;
    return (unsigned short)r;
}

// ---------------------------------------------------------------------------
// Detect whether edge_index arrived as int64 (stride 2 in int32 units) or
// int32 (stride 1). int64 values < 2^31 have all-zero high dwords.
__global__ void detect_kernel(const int* __restrict__ eidx, int* __restrict__ flag) {
    __shared__ int odd_nz;
    if (threadIdx.x == 0) odd_nz = 0;
    __syncthreads();
    int local = 0;
    for (int i = threadIdx.x; i < 2048; i += blockDim.x) {
        if (eidx[2 * i + 1] != 0) local = 1;
    }
    if (local) atomicOr(&odd_nz, 1);
    __syncthreads();
    if (threadIdx.x == 0) *flag = odd_nz ? 1 : 2;
}

// ---------------------------------------------------------------------------
// Coarse histogram of col>>BSHIFT (LDS per block, then global add).
__global__ void __launch_bounds__(256) chist_kernel(const int* __restrict__ eidx,
                                                    int* __restrict__ ghist,
                                                    const int* __restrict__ flag) {
    __shared__ int h[NBUCK];
    for (int i = threadIdx.x; i < NBUCK; i += 256) h[i] = 0;
    __syncthreads();
    int stride = *flag;
    long long cb = (long long)NEDGES * stride;
    int e0 = blockIdx.x * ECHUNK;
    int e1 = min(e0 + ECHUNK, NEDGES);
    for (int e = e0 + threadIdx.x; e < e1; e += 256) {
        int col = eidx[cb + (long long)e * stride];
        atomicAdd(&h[col >> BSHIFT], 1);
    }
    __syncthreads();
    for (int i = threadIdx.x; i < NBUCK; i += 256)
        if (h[i]) atomicAdd(&ghist[i], h[i]);
}

// ---------------------------------------------------------------------------
// One-block scan of the 391 coarse counts -> cbase[392] and cursor[391].
__global__ void __launch_bounds__(512) cscan_kernel(const int* __restrict__ ghist,
                                                    int* __restrict__ cbase,
                                                    int* __restrict__ cursor) {
    __shared__ int bufa[512], bufb[512];
    int t = threadIdx.x;
    bufa[t] = (t < NBUCK) ? ghist[t] : 0;
    __syncthreads();
    int* s = bufa; int* d = bufb;
    for (int off = 1; off < 512; off <<= 1) {
        d[t] = s[t] + ((t >= off) ? s[t - off] : 0);
        __syncthreads();
        int* tmp = s; s = d; d = tmp;
    }
    int excl = (t == 0) ? 0 : s[t - 1];
    if (t < NBUCK) { cbase[t] = excl; cursor[t] = excl; }
    if (t == NBUCK) cbase[t] = excl;
}

// ---------------------------------------------------------------------------
// Coarse scatter: group edges by col>>BSHIFT. Packed entry:
//   .x = (src << BSHIFT) | (col & (BSIZE-1))   (17+8 bits < 32)
//   .y = float bits of edge weight
__global__ void __launch_bounds__(256) cscatter_kernel(const int* __restrict__ eidx,
                                                       const float* __restrict__ ew,
                                                       int2* __restrict__ coarse,
                                                       int* __restrict__ cursor,
                                                       const int* __restrict__ flag) {
    __shared__ int h[NBUCK];
    __shared__ int lbase[NBUCK];
    for (int i = threadIdx.x; i < NBUCK; i += 256) h[i] = 0;
    __syncthreads();
    int stride = *flag;
    long long cb = (long long)NEDGES * stride;
    int e0 = blockIdx.x * ECHUNK;
    int e1 = min(e0 + ECHUNK, NEDGES);
    for (int e = e0 + threadIdx.x; e < e1; e += 256) {
        int col = eidx[cb + (long long)e * stride];
        atomicAdd(&h[col >> BSHIFT], 1);
    }
    __syncthreads();
    for (int i = threadIdx.x; i < NBUCK; i += 256) {
        int c = h[i];
        lbase[i] = c ? atomicAdd(&cursor[i], c) : 0;
        h[i] = 0;                      // reuse as local cursor
    }
    __syncthreads();
    for (int e = e0 + threadIdx.x; e < e1; e += 256) {
        int col = eidx[cb + (long long)e * stride];
        int src = eidx[(long long)e * stride];
        float w = ew[e];
        int bk = col >> BSHIFT;
        int pos = lbase[bk] + atomicAdd(&h[bk], 1);
        coarse[pos] = make_int2((src << BSHIFT) | (col & (BSIZE - 1)), __float_as_int(w));
    }
}

// ---------------------------------------------------------------------------
// Fine pass: one block per coarse bucket. Groups edges by exact col (LDS),
// computes weighted degree -> dinv (written globally), writes rowptr and
// CSR entries (src, w * dinv[col]).
__global__ void __launch_bounds__(256) fine_kernel(const int2* __restrict__ coarse,
                                                   const int* __restrict__ cbase,
                                                   int* __restrict__ rowptr,
                                                   float* __restrict__ dinv,
                                                   int2* __restrict__ csr) {
    __shared__ int hist[BSIZE];
    __shared__ float wdeg[BSIZE];
    __shared__ int foff[BSIZE];
    __shared__ int sa[BSIZE], sb[BSIZE];
    int t = threadIdx.x;
    int bk = blockIdx.x;
    hist[t] = 0;
    wdeg[t] = 0.f;
    __syncthreads();
    int eb = cbase[bk], ee = cbase[bk + 1];
    for (int i = eb + t; i < ee; i += 256) {
        int2 v = coarse[i];
        int loc = v.x & (BSIZE - 1);
        atomicAdd(&hist[loc], 1);
        atomicAdd(&wdeg[loc], __int_as_float(v.y));
    }
    __syncthreads();
    // dinv for this bucket's columns (deg + 1 self-loop)
    int gcol = (bk << BSHIFT) + t;
    float dv = rsqrtf(wdeg[t] + 1.0f);
    wdeg[t] = dv;                                  // now holds dinv[col]
    if (gcol < NNODES) dinv[gcol] = dv;
    // exclusive scan of hist -> foff
    sa[t] = hist[t];
    __syncthreads();
    int* s = sa; int* d = sb;
    for (int off = 1; off < BSIZE; off <<= 1) {
        d[t] = s[t] + ((t >= off) ? s[t - off] : 0);
        __syncthreads();
        int* tmp = s; s = d; d = tmp;
    }
    foff[t] = (t == 0) ? 0 : s[t - 1];
    hist[t] = 0;                                   // reuse as fine cursor
    __syncthreads();
    if (gcol <= NNODES) rowptr[gcol] = eb + foff[t];   // gcol==NNODES -> NEDGES
    for (int i = eb + t; i < ee; i += 256) {
        int2 v = coarse[i];
        int loc = v.x & (BSIZE - 1);
        int srcn = ((unsigned)v.x) >> BSHIFT;
        int pos = eb + foff[loc] + atomicAdd(&hist[loc], 1);
        csr[pos] = make_int2(srcn, __float_as_int(__int_as_float(v.y) * wdeg[loc]));
    }
}

// ---------------------------------------------------------------------------
// csr[e].y *= dinv[src]  (completes norm = dinv[src]*w*dinv[col])
__global__ void __launch_bounds__(256) fixup_kernel(int2* __restrict__ csr,
                                                    const float* __restrict__ dinv) {
    int e = blockIdx.x * 256 + threadIdx.x;
    if (e >= NEDGES) return;
    int2 v = csr[e];
    v.y = __float_as_int(__int_as_float(v.y) * dinv[v.x]);
    csr[e] = v;
}

// ---------------------------------------------------------------------------
// W (f32 [40][256]) -> WT bf16 [48][256], classes 40..47 zero-padded.
__global__ void wconv_kernel(const float* __restrict__ W, unsigned short* __restrict__ wt) {
    int i = blockIdx.x * 256 + threadIdx.x;
    if (i >= 48 * 256) return;
    int n = i >> 8;
    wt[i] = (n < NCLASS) ? f2bf(W[i]) : (unsigned short)0;
}

// ---------------------------------------------------------------------------
// MFMA projection: y0h[n, 0..39] = fp16( x[n,:] @ WT^T ), rows padded 128 B.
// Block = 4 waves; each wave: 16 nodes x 48 classes via 16x16x32 bf16 MFMA.
// No LDS. A-frags: 8 contiguous f32 of the x row per lane (2x float4),
// converted to bf16 in-register. B-frags: 16-B loads from L2-resident WT.
__global__ void __launch_bounds__(256) gemm_mfma_kernel(const float* __restrict__ x,
                                                        const unsigned short* __restrict__ wt,
                                                        __half* __restrict__ y0h) {
    int wv = threadIdx.x >> 6;
    int lane = threadIdx.x & 63;
    int r = lane & 15;           // A row / B col within tile
    int kg = lane >> 4;          // k-group 0..3
    int mbase = blockIdx.x * 64 + wv * 16;
    int anode = mbase + r;
    bool aok = anode < NNODES;
    const float* ap = x + (size_t)anode * NFEAT + kg * 8;

    f32x4 acc0 = {0.f, 0.f, 0.f, 0.f};
    f32x4 acc1 = {0.f, 0.f, 0.f, 0.f};
    f32x4 acc2 = {0.f, 0.f, 0.f, 0.f};
#pragma unroll
    for (int ks = 0; ks < 8; ks++) {
        int k0 = ks * 32 + kg * 8;
        bf16x8 af;
        if (aok) {
            float4 p0 = *(const float4*)(ap + ks * 32);
            float4 p1 = *(const float4*)(ap + ks * 32 + 4);
            af[0] = (short)f2bf(p0.x); af[1] = (short)f2bf(p0.y);
            af[2] = (short)f2bf(p0.z); af[3] = (short)f2bf(p0.w);
            af[4] = (short)f2bf(p1.x); af[5] = (short)f2bf(p1.y);
            af[6] = (short)f2bf(p1.z); af[7] = (short)f2bf(p1.w);
        } else {
            af = bf16x8{0, 0, 0, 0, 0, 0, 0, 0};
        }
        bf16x8 b0 = *(const bf16x8*)(wt + (0 * 16 + r) * NFEAT + k0);
        bf16x8 b1 = *(const bf16x8*)(wt + (1 * 16 + r) * NFEAT + k0);
        bf16x8 b2 = *(const bf16x8*)(wt + (2 * 16 + r) * NFEAT + k0);
        acc0 = __builtin_amdgcn_mfma_f32_16x16x32_bf16(af, b0, acc0, 0, 0, 0);
        acc1 = __builtin_amdgcn_mfma_f32_16x16x32_bf16(af, b1, acc1, 0, 0, 0);
        acc2 = __builtin_amdgcn_mfma_f32_16x16x32_bf16(af, b2, acc2, 0, 0, 0);
    }
    // C/D layout: col(class) = lane&15, row(node) = (lane>>4)*4 + reg
#pragma unroll
    for (int j = 0; j < 4; j++) {
        int node = mbase + kg * 4 + j;
        if (node >= NNODES) continue;
        __half* yr = y0h + (size_t)node * 64;
        yr[r] = __float2half_rn(acc0[j]);
        yr[16 + r] = __float2half_rn(acc1[j]);
        if (r < 8) yr[32 + r] = __float2half_rn(acc2[j]);
    }
}

// ---------------------------------------------------------------------------
// Hop (fp16 in / fp16 out): thread = (node, 4 classes). 32 nodes x 10 lanes.
// Edge loop unrolled 4x so 4 gathers are in flight per iteration.
__global__ void __launch_bounds__(320) hop16_kernel(const int* __restrict__ rowptr,
                                                    const int2* __restrict__ csr,
                                                    const float* __restrict__ dinv,
                                                    const uint2* __restrict__ yin,
                                                    uint2* __restrict__ yout) {
    int tid = threadIdx.x;
    int ln = tid / 10;
    int c4 = tid - ln * 10;
    int n = blockIdx.x * 32 + ln;
    float d = dinv[n];
    float dd = d * d;
    uint2 sv = yin[(size_t)n * ROWU2 + c4];
    float2 s01 = up2(sv.x), s23 = up2(sv.y);
    float a0 = dd * s01.x, a1 = dd * s01.y, a2 = dd * s23.x, a3 = dd * s23.y;
    int e0 = rowptr[n], e1 = rowptr[n + 1];
    int e = e0;
    for (; e + 4 <= e1; e += 4) {
        int2 p0 = csr[e], p1 = csr[e + 1], p2 = csr[e + 2], p3 = csr[e + 3];
        uint2 g0 = yin[(size_t)p0.x * ROWU2 + c4];
        uint2 g1 = yin[(size_t)p1.x * ROWU2 + c4];
        uint2 g2 = yin[(size_t)p2.x * ROWU2 + c4];
        uint2 g3 = yin[(size_t)p3.x * ROWU2 + c4];
        float w0 = __int_as_float(p0.y), w1 = __int_as_float(p1.y);
        float w2 = __int_as_float(p2.y), w3 = __int_as_float(p3.y);
        { float2 u = up2(g0.x), v = up2(g0.y); a0 += w0 * u.x; a1 += w0 * u.y; a2 += w0 * v.x; a3 += w0 * v.y; }
        { float2 u = up2(g1.x), v = up2(g1.y); a0 += w1 * u.x; a1 += w1 * u.y; a2 += w1 * v.x; a3 += w1 * v.y; }
        { float2 u = up2(g2.x), v = up2(g2.y); a0 += w2 * u.x; a1 += w2 * u.y; a2 += w2 * v.x; a3 += w2 * v.y; }
        { float2 u = up2(g3.x), v = up2(g3.y); a0 += w3 * u.x; a1 += w3 * u.y; a2 += w3 * v.x; a3 += w3 * v.y; }
    }
    for (; e < e1; e++) {
        int2 p = csr[e];
        uint2 g = yin[(size_t)p.x * ROWU2 + c4];
        float w = __int_as_float(p.y);
        float2 u = up2(g.x), v = up2(g.y);
        a0 += w * u.x; a1 += w * u.y; a2 += w * v.x; a3 += w * v.y;
    }
    yout[(size_t)n * ROWU2 + c4] = make_uint2(pk2(a0, a1), pk2(a2, a3));
}

// ---------------------------------------------------------------------------
// Final hop (fp16 in / f32 out) with bias + log_softmax fused.
__global__ void __launch_bounds__(320) hop32_kernel(const int* __restrict__ rowptr,
                                                    const int2* __restrict__ csr,
                                                    const float* __restrict__ dinv,
                                                    const uint2* __restrict__ yin,
                                                    const float* __restrict__ bias,
                                                    float* __restrict__ out) {
    __shared__ float redm[32][10];
    __shared__ float reds[32][10];
    int tid = threadIdx.x;
    int ln = tid / 10;
    int c4 = tid - ln * 10;
    int n = blockIdx.x * 32 + ln;          // NNODES == 3125*32, no tail
    float d = dinv[n];
    float dd = d * d;
    uint2 sv = yin[(size_t)n * ROWU2 + c4];
    float2 s01 = up2(sv.x), s23 = up2(sv.y);
    float a0 = dd * s01.x, a1 = dd * s01.y, a2 = dd * s23.x, a3 = dd * s23.y;
    int e0 = rowptr[n], e1 = rowptr[n + 1];
    int e = e0;
    for (; e + 4 <= e1; e += 4) {
        int2 p0 = csr[e], p1 = csr[e + 1], p2 = csr[e + 2], p3 = csr[e + 3];
        uint2 g0 = yin[(size_t)p0.x * ROWU2 + c4];
        uint2 g1 = yin[(size_t)p1.x * ROWU2 + c4];
        uint2 g2 = yin[(size_t)p2.x * ROWU2 + c4];
        uint2 g3 = yin[(size_t)p3.x * ROWU2 + c4];
        float w0 = __int_as_float(p0.y), w1 = __int_as_float(p1.y);
        float w2 = __int_as_float(p2.y), w3 = __int_as_float(p3.y);
        { float2 u = up2(g0.x), v = up2(g0.y); a0 += w0 * u.x; a1 += w0 * u.y; a2 += w0 * v.x; a3 += w0 * v.y; }
        { float2 u = up2(g1.x), v = up2(g1.y); a0 += w1 * u.x; a1 += w1 * u.y; a2 += w1 * v.x; a3 += w1 * v.y; }
        { float2 u = up2(g2.x), v = up2(g2.y); a0 += w2 * u.x; a1 += w2 * u.y; a2 += w2 * v.x; a3 += w2 * v.y; }
        { float2 u = up2(g3.x), v = up2(g3.y); a0 += w3 * u.x; a1 += w3 * u.y; a2 += w3 * v.x; a3 += w3 * v.y; }
    }
    for (; e < e1; e++) {
        int2 p = csr[e];
        uint2 g = yin[(size_t)p.x * ROWU2 + c4];
        float w = __int_as_float(p.y);
        float2 u = up2(g.x), v = up2(g.y);
        a0 += w * u.x; a1 += w * u.y; a2 += w * v.x; a3 += w * v.y;
    }
    // + bias
    float4 bb = *(const float4*)(bias + c4 * 4);
    float v0 = a0 + bb.x, v1 = a1 + bb.y, v2 = a2 + bb.z, v3 = a3 + bb.w;
    // log_softmax over the node's 40 classes (10 lanes x 4)
    redm[ln][c4] = fmaxf(fmaxf(v0, v1), fmaxf(v2, v3));
    __syncthreads();
    if (c4 == 0) {
        float m = redm[ln][0];
#pragma unroll
        for (int j = 1; j < 10; j++) m = fmaxf(m, redm[ln][j]);
        redm[ln][0] = m;
    }
    __syncthreads();
    float m = redm[ln][0];
    reds[ln][c4] = __expf(v0 - m) + __expf(v1 - m) + __expf(v2 - m) + __expf(v3 - m);
    __syncthreads();
    if (c4 == 0) {
        float s = 0.f;
#pragma unroll
        for (int j = 0; j < 10; j++) s += reds[ln][j];
        reds[ln][0] = logf(s);
    }
    __syncthreads();
    float ls = reds[ln][0];
    float4 r = make_float4(v0 - m - ls, v1 - m - ls, v2 - m - ls, v3 - m - ls);
    *(float4*)(out + (size_t)n * NCLASS + c4 * 4) = r;
}

// ---------------------------------------------------------------------------
extern "C" void kernel_launch(void* const* d_in, const int* in_sizes, int n_in,
                              void* d_out, int out_size, void* d_ws, size_t ws_size,
                              hipStream_t stream) {
    const float* x = (const float*)d_in[0];
    const int* eidx = (const int*)d_in[1];
    const float* ew = (const float*)d_in[2];
    const float* W = (const float*)d_in[3];
    const float* b = (const float*)d_in[4];
    float* out = (float*)d_out;

    char* ws = (char*)d_ws;
    size_t off = 0;
    auto alloc = [&](size_t bytes) -> char* {
        char* p = ws + off;
        off += (bytes + 255) & ~(size_t)255;
        return p;
    };
    int* flag = (int*)alloc(sizeof(int));
    int* ghist = (int*)alloc((size_t)NBUCK * 4);
    int* cbase = (int*)alloc((size_t)(NBUCK + 1) * 4);
    int* cursor = (int*)alloc((size_t)NBUCK * 4);
    int* rowptr = (int*)alloc((size_t)(NNODES + 1) * 4);
    float* dinv = (float*)alloc((size_t)NNODES * 4);
    unsigned short* wt = (unsigned short*)alloc((size_t)48 * 256 * 2);
    int2* csr = (int2*)alloc((size_t)NEDGES * 8);
    // coarse buffer (25.6 MB) aliases y0h+y1h (12.8 MB each): coarse is fully
    // consumed by fine_kernel before gemm writes y0h.
    char* un = alloc((size_t)NNODES * 128 * 2);
    int2* coarse = (int2*)un;
    __half* y0h = (__half*)un;
    uint2* y1h = (uint2*)(un + (size_t)NNODES * 128);

    hipMemsetAsync(ghist, 0, (size_t)NBUCK * 4, stream);
    detect_kernel<<<1, 256, 0, stream>>>(eidx, flag);
    wconv_kernel<<<48, 256, 0, stream>>>(W, wt);
    chist_kernel<<<NCB, 256, 0, stream>>>(eidx, ghist, flag);
    cscan_kernel<<<1, 512, 0, stream>>>(ghist, cbase, cursor);
    cscatter_kernel<<<NCB, 256, 0, stream>>>(eidx, ew, coarse, cursor, flag);
    fine_kernel<<<NBUCK, 256, 0, stream>>>(coarse, cbase, rowptr, dinv, csr);
    fixup_kernel<<<(NEDGES + 255) / 256, 256, 0, stream>>>(csr, dinv);
    // project features first: y0 = x @ W.T  (propagation and projection commute)
    gemm_mfma_kernel<<<(NNODES + 63) / 64, 256, 0, stream>>>(x, wt, y0h);
    // hop 1: y1 = A y0 (fp16 storage); hop 2: out = log_softmax(A y1 + b)
    hop16_kernel<<<NNODES / 32, 320, 0, stream>>>(rowptr, csr, dinv, (const uint2*)y0h, y1h);
    hop32_kernel<<<NNODES / 32, 320, 0, stream>>>(rowptr, csr, dinv, y1h, b, out);
}

// Round 6
// 287.068 us; speedup vs baseline: 4.9216x; 1.0035x over previous
//
#include <hip/hip_runtime.h>
#include <hip/hip_fp16.h>
#include <cmath>

#define NNODES 100000
#define NEDGES 3200000
#define NFEAT 256
#define NCLASS 40

#define BSHIFT 8
#define BSIZE 256                                  // nodes per coarse bucket
#define NBUCK ((NNODES + BSIZE - 1) / BSIZE)       // 391
#define ECHUNK 4096
#define NCB ((NEDGES + ECHUNK - 1) / ECHUNK)       // 782

// fp16 intermediate rows: 64 halves (128 B, one cache line), classes in 0..39
// Stored value is y' = dinv * y (pre-scaled), so CSR holds RAW edge weights.
#define ROWU2 16                                   // uint2 (4 halves) per row

using bf16x8 = __attribute__((ext_vector_type(8))) short;
using f32x4 = __attribute__((ext_vector_type(4))) float;

__device__ inline unsigned pk2(float a, float b) {
    __half2 h;
    h.x = __float2half_rn(a);
    h.y = __float2half_rn(b);
    return *reinterpret_cast<unsigned*>(&h);
}
__device__ inline float2 up2(unsigned u) {
    __half2 h = *reinterpret_cast<__half2*>(&u);
    float2 f;
    f.x = __half2float(h.x);
    f.y = __half2float(h.y);
    return f;
}
__device__ inline unsigned short f2bf(float f) {   // f32 -> bf16, round-nearest-even
    unsigned u = __float_as_uint(f);
    unsigned r = (u + 0x7FFFu + ((u >> 16) & 1u)) >> 16;
    return (unsigned short)r;
}

// ---------------------------------------------------------------------------
// Detect whether edge_index arrived as int64 (stride 2 in int32 units) or
// int32 (stride 1). int64 values < 2^31 have all-zero high dwords.
__global__ void detect_kernel(const int* __restrict__ eidx, int* __restrict__ flag) {
    __shared__ int odd_nz;
    if (threadIdx.x == 0) odd_nz = 0;
    __syncthreads();
    int local = 0;
    for (int i = threadIdx.x; i < 2048; i += blockDim.x) {
        if (eidx[2 * i + 1] != 0) local = 1;
    }
    if (local) atomicOr(&odd_nz, 1);
    __syncthreads();
    if (threadIdx.x == 0) *flag = odd_nz ? 1 : 2;
}

// ---------------------------------------------------------------------------
// Coarse histogram of col>>BSHIFT (LDS per block, then global add).
__global__ void __launch_bounds__(256) chist_kernel(const int* __restrict__ eidx,
                                                    int* __restrict__ ghist,
                                                    const int* __restrict__ flag) {
    __shared__ int h[NBUCK];
    for (int i = threadIdx.x; i < NBUCK; i += 256) h[i] = 0;
    __syncthreads();
    int stride = *flag;
    long long cb = (long long)NEDGES * stride;
    int e0 = blockIdx.x * ECHUNK;
    int e1 = min(e0 + ECHUNK, NEDGES);
    for (int e = e0 + threadIdx.x; e < e1; e += 256) {
        int col = eidx[cb + (long long)e * stride];
        atomicAdd(&h[col >> BSHIFT], 1);
    }
    __syncthreads();
    for (int i = threadIdx.x; i < NBUCK; i += 256)
        if (h[i]) atomicAdd(&ghist[i], h[i]);
}

// ---------------------------------------------------------------------------
// One-block scan of the 391 coarse counts -> cbase[392] and cursor[391].
__global__ void __launch_bounds__(512) cscan_kernel(const int* __restrict__ ghist,
                                                    int* __restrict__ cbase,
                                                    int* __restrict__ cursor) {
    __shared__ int bufa[512], bufb[512];
    int t = threadIdx.x;
    bufa[t] = (t < NBUCK) ? ghist[t] : 0;
    __syncthreads();
    int* s = bufa; int* d = bufb;
    for (int off = 1; off < 512; off <<= 1) {
        d[t] = s[t] + ((t >= off) ? s[t - off] : 0);
        __syncthreads();
        int* tmp = s; s = d; d = tmp;
    }
    int excl = (t == 0) ? 0 : s[t - 1];
    if (t < NBUCK) { cbase[t] = excl; cursor[t] = excl; }
    if (t == NBUCK) cbase[t] = excl;
}

// ---------------------------------------------------------------------------
// Coarse scatter: group edges by col>>BSHIFT. Packed entry:
//   .x = (src << BSHIFT) | (col & (BSIZE-1))   (17+8 bits < 32)
//   .y = float bits of edge weight
__global__ void __launch_bounds__(256) cscatter_kernel(const int* __restrict__ eidx,
                                                       const float* __restrict__ ew,
                                                       int2* __restrict__ coarse,
                                                       int* __restrict__ cursor,
                                                       const int* __restrict__ flag) {
    __shared__ int h[NBUCK];
    __shared__ int lbase[NBUCK];
    for (int i = threadIdx.x; i < NBUCK; i += 256) h[i] = 0;
    __syncthreads();
    int stride = *flag;
    long long cb = (long long)NEDGES * stride;
    int e0 = blockIdx.x * ECHUNK;
    int e1 = min(e0 + ECHUNK, NEDGES);
    for (int e = e0 + threadIdx.x; e < e1; e += 256) {
        int col = eidx[cb + (long long)e * stride];
        atomicAdd(&h[col >> BSHIFT], 1);
    }
    __syncthreads();
    for (int i = threadIdx.x; i < NBUCK; i += 256) {
        int c = h[i];
        lbase[i] = c ? atomicAdd(&cursor[i], c) : 0;
        h[i] = 0;                      // reuse as local cursor
    }
    __syncthreads();
    for (int e = e0 + threadIdx.x; e < e1; e += 256) {
        int col = eidx[cb + (long long)e * stride];
        int src = eidx[(long long)e * stride];
        float w = ew[e];
        int bk = col >> BSHIFT;
        int pos = lbase[bk] + atomicAdd(&h[bk], 1);
        coarse[pos] = make_int2((src << BSHIFT) | (col & (BSIZE - 1)), __float_as_int(w));
    }
}

// ---------------------------------------------------------------------------
// Fine pass: one block (512 thr) per coarse bucket. Groups edges by exact col
// (LDS), computes weighted degree -> dinv (written globally), writes rowptr
// and CSR entries (src, raw w).
__global__ void __launch_bounds__(512) fine_kernel(const int2* __restrict__ coarse,
                                                   const int* __restrict__ cbase,
                                                   int* __restrict__ rowptr,
                                                   float* __restrict__ dinv,
                                                   int2* __restrict__ csr) {
    __shared__ int hist[BSIZE];
    __shared__ float wdeg[BSIZE];
    __shared__ int foff[BSIZE];
    __shared__ int sa[BSIZE], sb[BSIZE];
    int t = threadIdx.x;
    int bk = blockIdx.x;
    if (t < BSIZE) { hist[t] = 0; wdeg[t] = 0.f; }
    __syncthreads();
    int eb = cbase[bk], ee = cbase[bk + 1];
    for (int i = eb + t; i < ee; i += 512) {
        int2 v = coarse[i];
        int loc = v.x & (BSIZE - 1);
        atomicAdd(&hist[loc], 1);
        atomicAdd(&wdeg[loc], __int_as_float(v.y));
    }
    __syncthreads();
    // dinv for this bucket's columns (deg + 1 self-loop)
    int gcol = (bk << BSHIFT) + t;
    if (t < BSIZE) {
        float dv = rsqrtf(wdeg[t] + 1.0f);
        wdeg[t] = dv;                              // now holds dinv[col]
        if (gcol < NNODES) dinv[gcol] = dv;
        sa[t] = hist[t];
    }
    __syncthreads();
    // exclusive scan of hist (256 entries) -> foff; all 512 threads hit barriers
    int* s = sa; int* d = sb;
    for (int off = 1; off < BSIZE; off <<= 1) {
        if (t < BSIZE) d[t] = s[t] + ((t >= off) ? s[t - off] : 0);
        __syncthreads();
        int* tmp = s; s = d; d = tmp;
    }
    if (t < BSIZE) {
        foff[t] = (t == 0) ? 0 : s[t - 1];
        hist[t] = 0;                               // reuse as fine cursor
        if (gcol <= NNODES) rowptr[gcol] = eb + foff[t];   // gcol==NNODES -> NEDGES
    }
    __syncthreads();
    for (int i = eb + t; i < ee; i += 512) {
        int2 v = coarse[i];
        int loc = v.x & (BSIZE - 1);
        int srcn = ((unsigned)v.x) >> BSHIFT;
        int pos = eb + foff[loc] + atomicAdd(&hist[loc], 1);
        csr[pos] = make_int2(srcn, v.y);           // raw edge weight
    }
}

// ---------------------------------------------------------------------------
// W (f32 [40][256]) -> WT bf16 [48][256], classes 40..47 zero-padded.
__global__ void wconv_kernel(const float* __restrict__ W, unsigned short* __restrict__ wt) {
    int i = blockIdx.x * 256 + threadIdx.x;
    if (i >= 48 * 256) return;
    int n = i >> 8;
    wt[i] = (n < NCLASS) ? f2bf(W[i]) : (unsigned short)0;
}

// ---------------------------------------------------------------------------
// MFMA projection: y0h[n, 0..39] = fp16( dinv[n] * (x[n,:] @ WT^T) ).
// Block = 4 waves; each wave: 16 nodes x 48 classes via 16x16x32 bf16 MFMA.
__global__ void __launch_bounds__(256) gemm_mfma_kernel(const float* __restrict__ x,
                                                        const unsigned short* __restrict__ wt,
                                                        const float* __restrict__ dinv,
                                                        __half* __restrict__ y0h) {
    int wv = threadIdx.x >> 6;
    int lane = threadIdx.x & 63;
    int r = lane & 15;           // A row / B col within tile
    int kg = lane >> 4;          // k-group 0..3
    int mbase = blockIdx.x * 64 + wv * 16;
    int anode = mbase + r;
    bool aok = anode < NNODES;
    const float* ap = x + (size_t)anode * NFEAT + kg * 8;

    f32x4 acc0 = {0.f, 0.f, 0.f, 0.f};
    f32x4 acc1 = {0.f, 0.f, 0.f, 0.f};
    f32x4 acc2 = {0.f, 0.f, 0.f, 0.f};
#pragma unroll
    for (int ks = 0; ks < 8; ks++) {
        int k0 = ks * 32 + kg * 8;
        bf16x8 af;
        if (aok) {
            float4 p0 = *(const float4*)(ap + ks * 32);
            float4 p1 = *(const float4*)(ap + ks * 32 + 4);
            af[0] = (short)f2bf(p0.x); af[1] = (short)f2bf(p0.y);
            af[2] = (short)f2bf(p0.z); af[3] = (short)f2bf(p0.w);
            af[4] = (short)f2bf(p1.x); af[5] = (short)f2bf(p1.y);
            af[6] = (short)f2bf(p1.z); af[7] = (short)f2bf(p1.w);
        } else {
            af = bf16x8{0, 0, 0, 0, 0, 0, 0, 0};
        }
        bf16x8 b0 = *(const bf16x8*)(wt + (0 * 16 + r) * NFEAT + k0);
        bf16x8 b1 = *(const bf16x8*)(wt + (1 * 16 + r) * NFEAT + k0);
        bf16x8 b2 = *(const bf16x8*)(wt + (2 * 16 + r) * NFEAT + k0);
        acc0 = __builtin_amdgcn_mfma_f32_16x16x32_bf16(af, b0, acc0, 0, 0, 0);
        acc1 = __builtin_amdgcn_mfma_f32_16x16x32_bf16(af, b1, acc1, 0, 0, 0);
        acc2 = __builtin_amdgcn_mfma_f32_16x16x32_bf16(af, b2, acc2, 0, 0, 0);
    }
    // C/D layout: col(class) = lane&15, row(node) = (lane>>4)*4 + reg
#pragma unroll
    for (int j = 0; j < 4; j++) {
        int node = mbase + kg * 4 + j;
        if (node >= NNODES) continue;
        float dv = dinv[node];
        __half* yr = y0h + (size_t)node * 64;
        yr[r] = __float2half_rn(acc0[j] * dv);
        yr[16 + r] = __float2half_rn(acc1[j] * dv);
        if (r < 8) yr[32 + r] = __float2half_rn(acc2[j] * dv);
    }
}

// ---------------------------------------------------------------------------
// Hop (y' in / y' out): thread = (node, 4 classes). 32 nodes x 10 lanes.
// acc = y'[self] + sum_e w_e * y'[src];  store dinv[n]^2 * acc.
__global__ void __launch_bounds__(320) hop16_kernel(const int* __restrict__ rowptr,
                                                    const int2* __restrict__ csr,
                                                    const float* __restrict__ dinv,
                                                    const uint2* __restrict__ yin,
                                                    uint2* __restrict__ yout) {
    int tid = threadIdx.x;
    int ln = tid / 10;
    int c4 = tid - ln * 10;
    int n = blockIdx.x * 32 + ln;
    float d = dinv[n];
    float dd = d * d;
    uint2 sv = yin[(size_t)n * ROWU2 + c4];
    float2 s01 = up2(sv.x), s23 = up2(sv.y);
    float a0 = s01.x, a1 = s01.y, a2 = s23.x, a3 = s23.y;
    int e0 = rowptr[n], e1 = rowptr[n + 1];
    int e = e0;
    for (; e + 4 <= e1; e += 4) {
        int2 p0 = csr[e], p1 = csr[e + 1], p2 = csr[e + 2], p3 = csr[e + 3];
        uint2 g0 = yin[(size_t)p0.x * ROWU2 + c4];
        uint2 g1 = yin[(size_t)p1.x * ROWU2 + c4];
        uint2 g2 = yin[(size_t)p2.x * ROWU2 + c4];
        uint2 g3 = yin[(size_t)p3.x * ROWU2 + c4];
        float w0 = __int_as_float(p0.y), w1 = __int_as_float(p1.y);
        float w2 = __int_as_float(p2.y), w3 = __int_as_float(p3.y);
        { float2 u = up2(g0.x), v = up2(g0.y); a0 += w0 * u.x; a1 += w0 * u.y; a2 += w0 * v.x; a3 += w0 * v.y; }
        { float2 u = up2(g1.x), v = up2(g1.y); a0 += w1 * u.x; a1 += w1 * u.y; a2 += w1 * v.x; a3 += w1 * v.y; }
        { float2 u = up2(g2.x), v = up2(g2.y); a0 += w2 * u.x; a1 += w2 * u.y; a2 += w2 * v.x; a3 += w2 * v.y; }
        { float2 u = up2(g3.x), v = up2(g3.y); a0 += w3 * u.x; a1 += w3 * u.y; a2 += w3 * v.x; a3 += w3 * v.y; }
    }
    for (; e < e1; e++) {
        int2 p = csr[e];
        uint2 g = yin[(size_t)p.x * ROWU2 + c4];
        float w = __int_as_float(p.y);
        float2 u = up2(g.x), v = up2(g.y);
        a0 += w * u.x; a1 += w * u.y; a2 += w * v.x; a3 += w * v.y;
    }
    yout[(size_t)n * ROWU2 + c4] = make_uint2(pk2(dd * a0, dd * a1), pk2(dd * a2, dd * a3));
}

// ---------------------------------------------------------------------------
// Final hop (y' in / f32 out): logits = dinv[n]*acc + bias, then log_softmax.
__global__ void __launch_bounds__(320) hop32_kernel(const int* __restrict__ rowptr,
                                                    const int2* __restrict__ csr,
                                                    const float* __restrict__ dinv,
                                                    const uint2* __restrict__ yin,
                                                    const float* __restrict__ bias,
                                                    float* __restrict__ out) {
    __shared__ float redm[32][10];
    __shared__ float reds[32][10];
    int tid = threadIdx.x;
    int ln = tid / 10;
    int c4 = tid - ln * 10;
    int n = blockIdx.x * 32 + ln;          // NNODES == 3125*32, no tail
    float d = dinv[n];
    uint2 sv = yin[(size_t)n * ROWU2 + c4];
    float2 s01 = up2(sv.x), s23 = up2(sv.y);
    float a0 = s01.x, a1 = s01.y, a2 = s23.x, a3 = s23.y;
    int e0 = rowptr[n], e1 = rowptr[n + 1];
    int e = e0;
    for (; e + 4 <= e1; e += 4) {
        int2 p0 = csr[e], p1 = csr[e + 1], p2 = csr[e + 2], p3 = csr[e + 3];
        uint2 g0 = yin[(size_t)p0.x * ROWU2 + c4];
        uint2 g1 = yin[(size_t)p1.x * ROWU2 + c4];
        uint2 g2 = yin[(size_t)p2.x * ROWU2 + c4];
        uint2 g3 = yin[(size_t)p3.x * ROWU2 + c4];
        float w0 = __int_as_float(p0.y), w1 = __int_as_float(p1.y);
        float w2 = __int_as_float(p2.y), w3 = __int_as_float(p3.y);
        { float2 u = up2(g0.x), v = up2(g0.y); a0 += w0 * u.x; a1 += w0 * u.y; a2 += w0 * v.x; a3 += w0 * v.y; }
        { float2 u = up2(g1.x), v = up2(g1.y); a0 += w1 * u.x; a1 += w1 * u.y; a2 += w1 * v.x; a3 += w1 * v.y; }
        { float2 u = up2(g2.x), v = up2(g2.y); a0 += w2 * u.x; a1 += w2 * u.y; a2 += w2 * v.x; a3 += w2 * v.y; }
        { float2 u = up2(g3.x), v = up2(g3.y); a0 += w3 * u.x; a1 += w3 * u.y; a2 += w3 * v.x; a3 += w3 * v.y; }
    }
    for (; e < e1; e++) {
        int2 p = csr[e];
        uint2 g = yin[(size_t)p.x * ROWU2 + c4];
        float w = __int_as_float(p.y);
        float2 u = up2(g.x), v = up2(g.y);
        a0 += w * u.x; a1 += w * u.y; a2 += w * v.x; a3 += w * v.y;
    }
    // logits = dinv * acc + bias
    float4 bb = *(const float4*)(bias + c4 * 4);
    float v0 = d * a0 + bb.x, v1 = d * a1 + bb.y, v2 = d * a2 + bb.z, v3 = d * a3 + bb.w;
    // log_softmax over the node's 40 classes (10 lanes x 4)
    redm[ln][c4] = fmaxf(fmaxf(v0, v1), fmaxf(v2, v3));
    __syncthreads();
    if (c4 == 0) {
        float m = redm[ln][0];
#pragma unroll
        for (int j = 1; j < 10; j++) m = fmaxf(m, redm[ln][j]);
        redm[ln][0] = m;
    }
    __syncthreads();
    float m = redm[ln][0];
    reds[ln][c4] = __expf(v0 - m) + __expf(v1 - m) + __expf(v2 - m) + __expf(v3 - m);
    __syncthreads();
    if (c4 == 0) {
        float s = 0.f;
#pragma unroll
        for (int j = 0; j < 10; j++) s += reds[ln][j];
        reds[ln][0] = logf(s);
    }
    __syncthreads();
    float ls = reds[ln][0];
    float4 r = make_float4(v0 - m - ls, v1 - m - ls, v2 - m - ls, v3 - m - ls);
    *(float4*)(out + (size_t)n * NCLASS + c4 * 4) = r;
}

// ---------------------------------------------------------------------------
extern "C" void kernel_launch(void* const* d_in, const int* in_sizes, int n_in,
                              void* d_out, int out_size, void* d_ws, size_t ws_size,
                              hipStream_t stream) {
    const float* x = (const float*)d_in[0];
    const int* eidx = (const int*)d_in[1];
    const float* ew = (const float*)d_in[2];
    const float* W = (const float*)d_in[3];
    const float* b = (const float*)d_in[4];
    float* out = (float*)d_out;

    char* ws = (char*)d_ws;
    size_t off = 0;
    auto alloc = [&](size_t bytes) -> char* {
        char* p = ws + off;
        off += (bytes + 255) & ~(size_t)255;
        return p;
    };
    int* flag = (int*)alloc(sizeof(int));
    int* ghist = (int*)alloc((size_t)NBUCK * 4);
    int* cbase = (int*)alloc((size_t)(NBUCK + 1) * 4);
    int* cursor = (int*)alloc((size_t)NBUCK * 4);
    int* rowptr = (int*)alloc((size_t)(NNODES + 1) * 4);
    float* dinv = (float*)alloc((size_t)NNODES * 4);
    unsigned short* wt = (unsigned short*)alloc((size_t)48 * 256 * 2);
    int2* csr = (int2*)alloc((size_t)NEDGES * 8);
    // coarse buffer (25.6 MB) aliases y0h+y1h (12.8 MB each): coarse is fully
    // consumed by fine_kernel before gemm writes y0h.
    char* un = alloc((size_t)NNODES * 128 * 2);
    int2* coarse = (int2*)un;
    __half* y0h = (__half*)un;
    uint2* y1h = (uint2*)(un + (size_t)NNODES * 128);

    hipMemsetAsync(ghist, 0, (size_t)NBUCK * 4, stream);
    detect_kernel<<<1, 256, 0, stream>>>(eidx, flag);
    wconv_kernel<<<48, 256, 0, stream>>>(W, wt);
    chist_kernel<<<NCB, 256, 0, stream>>>(eidx, ghist, flag);
    cscan_kernel<<<1, 512, 0, stream>>>(ghist, cbase, cursor);
    cscatter_kernel<<<NCB, 256, 0, stream>>>(eidx, ew, coarse, cursor, flag);
    fine_kernel<<<NBUCK, 512, 0, stream>>>(coarse, cbase, rowptr, dinv, csr);
    // project features first: y0' = dinv * (x @ W.T)  (propagation commutes)
    gemm_mfma_kernel<<<(NNODES + 63) / 64, 256, 0, stream>>>(x, wt, dinv, y0h);
    // hop 1: y1' = dinv^2 (y0'[self] + A_w y0');  hop 2: out = log_softmax(dinv(...) + b)
    hop16_kernel<<<NNODES / 32, 320, 0, stream>>>(rowptr, csr, dinv, (const uint2*)y0h, y1h);
    hop32_kernel<<<NNODES / 32, 320, 0, stream>>>(rowptr, csr, dinv, y1h, b, out);
}

// Round 7
// 248.626 us; speedup vs baseline: 5.6825x; 1.1546x over previous
//
#include <hip/hip_runtime.h>
#include <hip/hip_fp16.h>
#include <cmath>

#define NNODES 100000
#define NEDGES 3200000
#define NFEAT 256
#define NCLASS 40

#define BSHIFT 8
#define BSIZE 256                                  // nodes per coarse bucket
#define NBUCK ((NNODES + BSIZE - 1) / BSIZE)       // 391
#define ECHUNK 8192
#define CSTH 512
#define EPT (ECHUNK / CSTH)                        // 16 edges per thread
#define NCB ((NEDGES + ECHUNK - 1) / ECHUNK)       // 391

// fp16 intermediate rows: 64 halves (128 B, one cache line), classes in 0..39
// Stored value is y' = dinv * y (pre-scaled), so CSR holds RAW edge weights.
#define ROWU2 16                                   // uint2 (4 halves) per row

using bf16x8 = __attribute__((ext_vector_type(8))) short;
using f32x4 = __attribute__((ext_vector_type(4))) float;

__device__ inline unsigned pk2(float a, float b) {
    __half2 h;
    h.x = __float2half_rn(a);
    h.y = __float2half_rn(b);
    return *reinterpret_cast<unsigned*>(&h);
}
__device__ inline float2 up2(unsigned u) {
    __half2 h = *reinterpret_cast<__half2*>(&u);
    float2 f;
    f.x = __half2float(h.x);
    f.y = __half2float(h.y);
    return f;
}
__device__ inline unsigned short f2bf(float f) {   // f32 -> bf16, round-nearest-even
    unsigned u = __float_as_uint(f);
    unsigned r = (u + 0x7FFFu + ((u >> 16) & 1u)) >> 16;
    return (unsigned short)r;
}

// ---------------------------------------------------------------------------
// Detect whether edge_index arrived as int64 (stride 2 in int32 units) or
// int32 (stride 1). int64 values < 2^31 have all-zero high dwords.
__global__ void detect_kernel(const int* __restrict__ eidx, int* __restrict__ flag) {
    __shared__ int odd_nz;
    if (threadIdx.x == 0) odd_nz = 0;
    __syncthreads();
    int local = 0;
    for (int i = threadIdx.x; i < 2048; i += blockDim.x) {
        if (eidx[2 * i + 1] != 0) local = 1;
    }
    if (local) atomicOr(&odd_nz, 1);
    __syncthreads();
    if (threadIdx.x == 0) *flag = odd_nz ? 1 : 2;
}

// ---------------------------------------------------------------------------
// Coarse histogram of col>>BSHIFT (LDS per block, then global add).
__global__ void __launch_bounds__(CSTH) chist_kernel(const int* __restrict__ eidx,
                                                     int* __restrict__ ghist,
                                                     const int* __restrict__ flag) {
    __shared__ int h[NBUCK];
    for (int i = threadIdx.x; i < NBUCK; i += CSTH) h[i] = 0;
    __syncthreads();
    int stride = *flag;
    long long cb = (long long)NEDGES * stride;
    int e0 = blockIdx.x * ECHUNK;
    int e1 = min(e0 + ECHUNK, NEDGES);
    for (int e = e0 + threadIdx.x; e < e1; e += CSTH) {
        int col = eidx[cb + (long long)e * stride];
        atomicAdd(&h[col >> BSHIFT], 1);
    }
    __syncthreads();
    for (int i = threadIdx.x; i < NBUCK; i += CSTH)
        if (h[i]) atomicAdd(&ghist[i], h[i]);
}

// ---------------------------------------------------------------------------
// One-block scan of the 391 coarse counts -> cbase[392] and cursor[391].
__global__ void __launch_bounds__(512) cscan_kernel(const int* __restrict__ ghist,
                                                    int* __restrict__ cbase,
                                                    int* __restrict__ cursor) {
    __shared__ int bufa[512], bufb[512];
    int t = threadIdx.x;
    bufa[t] = (t < NBUCK) ? ghist[t] : 0;
    __syncthreads();
    int* s = bufa; int* d = bufb;
    for (int off = 1; off < 512; off <<= 1) {
        d[t] = s[t] + ((t >= off) ? s[t - off] : 0);
        __syncthreads();
        int* tmp = s; s = d; d = tmp;
    }
    int excl = (t == 0) ? 0 : s[t - 1];
    if (t < NBUCK) { cbase[t] = excl; cursor[t] = excl; }
    if (t == NBUCK) cbase[t] = excl;
}

// ---------------------------------------------------------------------------
// Coarse scatter: group edges by col>>BSHIFT. Register-staged: the chunk's
// (bucket, packed, weight) live in VGPRs between the histogram and the
// placement pass, so eidx is read ONCE. Packed entry:
//   .x = (src << BSHIFT) | (col & (BSIZE-1))   (17+8 bits < 32)
//   .y = float bits of edge weight
__global__ void __launch_bounds__(CSTH) cscatter_kernel(const int* __restrict__ eidx,
                                                        const float* __restrict__ ew,
                                                        int2* __restrict__ coarse,
                                                        int* __restrict__ cursor,
                                                        const int* __restrict__ flag) {
    __shared__ int h[NBUCK];
    __shared__ int lbase[NBUCK];
    int t = threadIdx.x;
    for (int i = t; i < NBUCK; i += CSTH) h[i] = 0;
    __syncthreads();
    int stride = *flag;
    long long cb = (long long)NEDGES * stride;
    int e0 = blockIdx.x * ECHUNK;
    int bk[EPT];
    int pk[EPT];
    float wv[EPT];
#pragma unroll
    for (int i = 0; i < EPT; i++) {
        int e = e0 + t + i * CSTH;
        if (e < NEDGES) {
            int col = eidx[cb + (long long)e * stride];
            int src = eidx[(long long)e * stride];
            wv[i] = ew[e];
            bk[i] = col >> BSHIFT;
            pk[i] = (src << BSHIFT) | (col & (BSIZE - 1));
            atomicAdd(&h[bk[i]], 1);
        } else {
            bk[i] = -1;
        }
    }
    __syncthreads();
    for (int i = t; i < NBUCK; i += CSTH) {
        int c = h[i];
        lbase[i] = c ? atomicAdd(&cursor[i], c) : 0;
        h[i] = 0;                      // reuse as local cursor
    }
    __syncthreads();
#pragma unroll
    for (int i = 0; i < EPT; i++) {
        if (bk[i] >= 0) {
            int pos = lbase[bk[i]] + atomicAdd(&h[bk[i]], 1);
            coarse[pos] = make_int2(pk[i], __float_as_int(wv[i]));
        }
    }
}

// ---------------------------------------------------------------------------
// Fine pass: one block (512 thr) per coarse bucket. Groups edges by exact col
// (LDS), computes weighted degree -> dinv (written globally), writes rowptr
// and CSR entries (src, raw w).
__global__ void __launch_bounds__(512) fine_kernel(const int2* __restrict__ coarse,
                                                   const int* __restrict__ cbase,
                                                   int* __restrict__ rowptr,
                                                   float* __restrict__ dinv,
                                                   int2* __restrict__ csr) {
    __shared__ int hist[BSIZE];
    __shared__ float wdeg[BSIZE];
    __shared__ int foff[BSIZE];
    __shared__ int sa[BSIZE], sb[BSIZE];
    int t = threadIdx.x;
    int bk = blockIdx.x;
    if (t < BSIZE) { hist[t] = 0; wdeg[t] = 0.f; }
    __syncthreads();
    int eb = cbase[bk], ee = cbase[bk + 1];
    for (int i = eb + t; i < ee; i += 512) {
        int2 v = coarse[i];
        int loc = v.x & (BSIZE - 1);
        atomicAdd(&hist[loc], 1);
        atomicAdd(&wdeg[loc], __int_as_float(v.y));
    }
    __syncthreads();
    // dinv for this bucket's columns (deg + 1 self-loop)
    int gcol = (bk << BSHIFT) + t;
    if (t < BSIZE) {
        float dv = rsqrtf(wdeg[t] + 1.0f);
        wdeg[t] = dv;                              // now holds dinv[col]
        if (gcol < NNODES) dinv[gcol] = dv;
        sa[t] = hist[t];
    }
    __syncthreads();
    // exclusive scan of hist (256 entries) -> foff; all 512 threads hit barriers
    int* s = sa; int* d = sb;
    for (int off = 1; off < BSIZE; off <<= 1) {
        if (t < BSIZE) d[t] = s[t] + ((t >= off) ? s[t - off] : 0);
        __syncthreads();
        int* tmp = s; s = d; d = tmp;
    }
    if (t < BSIZE) {
        foff[t] = (t == 0) ? 0 : s[t - 1];
        hist[t] = 0;                               // reuse as fine cursor
        if (gcol <= NNODES) rowptr[gcol] = eb + foff[t];   // gcol==NNODES -> NEDGES
    }
    __syncthreads();
    for (int i = eb + t; i < ee; i += 512) {
        int2 v = coarse[i];
        int loc = v.x & (BSIZE - 1);
        int srcn = ((unsigned)v.x) >> BSHIFT;
        int pos = eb + foff[loc] + atomicAdd(&hist[loc], 1);
        csr[pos] = make_int2(srcn, v.y);           // raw edge weight
    }
}

// ---------------------------------------------------------------------------
// W (f32 [40][256]) -> WT bf16 [48][256], classes 40..47 zero-padded.
__global__ void wconv_kernel(const float* __restrict__ W, unsigned short* __restrict__ wt) {
    int i = blockIdx.x * 256 + threadIdx.x;
    if (i >= 48 * 256) return;
    int n = i >> 8;
    wt[i] = (n < NCLASS) ? f2bf(W[i]) : (unsigned short)0;
}

// ---------------------------------------------------------------------------
// MFMA projection: y0h[n, 0..39] = fp16( dinv[n] * (x[n,:] @ WT^T) ).
// Block = 4 waves; each wave: 16 nodes x 48 classes via 16x16x32 bf16 MFMA.
__global__ void __launch_bounds__(256) gemm_mfma_kernel(const float* __restrict__ x,
                                                        const unsigned short* __restrict__ wt,
                                                        const float* __restrict__ dinv,
                                                        __half* __restrict__ y0h) {
    int wv = threadIdx.x >> 6;
    int lane = threadIdx.x & 63;
    int r = lane & 15;           // A row / B col within tile
    int kg = lane >> 4;          // k-group 0..3
    int mbase = blockIdx.x * 64 + wv * 16;
    int anode = mbase + r;
    bool aok = anode < NNODES;
    const float* ap = x + (size_t)anode * NFEAT + kg * 8;

    f32x4 acc0 = {0.f, 0.f, 0.f, 0.f};
    f32x4 acc1 = {0.f, 0.f, 0.f, 0.f};
    f32x4 acc2 = {0.f, 0.f, 0.f, 0.f};
#pragma unroll
    for (int ks = 0; ks < 8; ks++) {
        int k0 = ks * 32 + kg * 8;
        bf16x8 af;
        if (aok) {
            float4 p0 = *(const float4*)(ap + ks * 32);
            float4 p1 = *(const float4*)(ap + ks * 32 + 4);
            af[0] = (short)f2bf(p0.x); af[1] = (short)f2bf(p0.y);
            af[2] = (short)f2bf(p0.z); af[3] = (short)f2bf(p0.w);
            af[4] = (short)f2bf(p1.x); af[5] = (short)f2bf(p1.y);
            af[6] = (short)f2bf(p1.z); af[7] = (short)f2bf(p1.w);
        } else {
            af = bf16x8{0, 0, 0, 0, 0, 0, 0, 0};
        }
        bf16x8 b0 = *(const bf16x8*)(wt + (0 * 16 + r) * NFEAT + k0);
        bf16x8 b1 = *(const bf16x8*)(wt + (1 * 16 + r) * NFEAT + k0);
        bf16x8 b2 = *(const bf16x8*)(wt + (2 * 16 + r) * NFEAT + k0);
        acc0 = __builtin_amdgcn_mfma_f32_16x16x32_bf16(af, b0, acc0, 0, 0, 0);
        acc1 = __builtin_amdgcn_mfma_f32_16x16x32_bf16(af, b1, acc1, 0, 0, 0);
        acc2 = __builtin_amdgcn_mfma_f32_16x16x32_bf16(af, b2, acc2, 0, 0, 0);
    }
    // C/D layout: col(class) = lane&15, row(node) = (lane>>4)*4 + reg
#pragma unroll
    for (int j = 0; j < 4; j++) {
        int node = mbase + kg * 4 + j;
        if (node >= NNODES) continue;
        float dv = dinv[node];
        __half* yr = y0h + (size_t)node * 64;
        yr[r] = __float2half_rn(acc0[j] * dv);
        yr[16 + r] = __float2half_rn(acc1[j] * dv);
        if (r < 8) yr[32 + r] = __float2half_rn(acc2[j] * dv);
    }
}

// ---------------------------------------------------------------------------
// Hop (y' in / y' out): thread = (node, 4 classes). 32 nodes x 10 lanes.
// acc = y'[self] + sum_e w_e * y'[src];  store dinv[n]^2 * acc.
// Edge loop unrolled 8x: 8 csr reads then 8 independent gathers in flight.
__global__ void __launch_bounds__(320) hop16_kernel(const int* __restrict__ rowptr,
                                                    const int2* __restrict__ csr,
                                                    const float* __restrict__ dinv,
                                                    const uint2* __restrict__ yin,
                                                    uint2* __restrict__ yout) {
    int tid = threadIdx.x;
    int ln = tid / 10;
    int c4 = tid - ln * 10;
    int n = blockIdx.x * 32 + ln;
    float d = dinv[n];
    float dd = d * d;
    uint2 sv = yin[(size_t)n * ROWU2 + c4];
    float2 s01 = up2(sv.x), s23 = up2(sv.y);
    float a0 = s01.x, a1 = s01.y, a2 = s23.x, a3 = s23.y;
    int e0 = rowptr[n], e1 = rowptr[n + 1];
    int e = e0;
    for (; e + 8 <= e1; e += 8) {
        int2 p[8];
        uint2 g[8];
#pragma unroll
        for (int i = 0; i < 8; i++) p[i] = csr[e + i];
#pragma unroll
        for (int i = 0; i < 8; i++) g[i] = yin[(size_t)p[i].x * ROWU2 + c4];
#pragma unroll
        for (int i = 0; i < 8; i++) {
            float w = __int_as_float(p[i].y);
            float2 u = up2(g[i].x), v = up2(g[i].y);
            a0 += w * u.x; a1 += w * u.y; a2 += w * v.x; a3 += w * v.y;
        }
    }
    for (; e + 4 <= e1; e += 4) {
        int2 p0 = csr[e], p1 = csr[e + 1], p2 = csr[e + 2], p3 = csr[e + 3];
        uint2 g0 = yin[(size_t)p0.x * ROWU2 + c4];
        uint2 g1 = yin[(size_t)p1.x * ROWU2 + c4];
        uint2 g2 = yin[(size_t)p2.x * ROWU2 + c4];
        uint2 g3 = yin[(size_t)p3.x * ROWU2 + c4];
        float w0 = __int_as_float(p0.y), w1 = __int_as_float(p1.y);
        float w2 = __int_as_float(p2.y), w3 = __int_as_float(p3.y);
        { float2 u = up2(g0.x), v = up2(g0.y); a0 += w0 * u.x; a1 += w0 * u.y; a2 += w0 * v.x; a3 += w0 * v.y; }
        { float2 u = up2(g1.x), v = up2(g1.y); a0 += w1 * u.x; a1 += w1 * u.y; a2 += w1 * v.x; a3 += w1 * v.y; }
        { float2 u = up2(g2.x), v = up2(g2.y); a0 += w2 * u.x; a1 += w2 * u.y; a2 += w2 * v.x; a3 += w2 * v.y; }
        { float2 u = up2(g3.x), v = up2(g3.y); a0 += w3 * u.x; a1 += w3 * u.y; a2 += w3 * v.x; a3 += w3 * v.y; }
    }
    for (; e < e1; e++) {
        int2 p = csr[e];
        uint2 g = yin[(size_t)p.x * ROWU2 + c4];
        float w = __int_as_float(p.y);
        float2 u = up2(g.x), v = up2(g.y);
        a0 += w * u.x; a1 += w * u.y; a2 += w * v.x; a3 += w * v.y;
    }
    yout[(size_t)n * ROWU2 + c4] = make_uint2(pk2(dd * a0, dd * a1), pk2(dd * a2, dd * a3));
}

// ---------------------------------------------------------------------------
// Final hop (y' in / f32 out): logits = dinv[n]*acc + bias, then log_softmax.
__global__ void __launch_bounds__(320) hop32_kernel(const int* __restrict__ rowptr,
                                                    const int2* __restrict__ csr,
                                                    const float* __restrict__ dinv,
                                                    const uint2* __restrict__ yin,
                                                    const float* __restrict__ bias,
                                                    float* __restrict__ out) {
    __shared__ float redm[32][10];
    __shared__ float reds[32][10];
    int tid = threadIdx.x;
    int ln = tid / 10;
    int c4 = tid - ln * 10;
    int n = blockIdx.x * 32 + ln;          // NNODES == 3125*32, no tail
    float d = dinv[n];
    uint2 sv = yin[(size_t)n * ROWU2 + c4];
    float2 s01 = up2(sv.x), s23 = up2(sv.y);
    float a0 = s01.x, a1 = s01.y, a2 = s23.x, a3 = s23.y;
    int e0 = rowptr[n], e1 = rowptr[n + 1];
    int e = e0;
    for (; e + 8 <= e1; e += 8) {
        int2 p[8];
        uint2 g[8];
#pragma unroll
        for (int i = 0; i < 8; i++) p[i] = csr[e + i];
#pragma unroll
        for (int i = 0; i < 8; i++) g[i] = yin[(size_t)p[i].x * ROWU2 + c4];
#pragma unroll
        for (int i = 0; i < 8; i++) {
            float w = __int_as_float(p[i].y);
            float2 u = up2(g[i].x), v = up2(g[i].y);
            a0 += w * u.x; a1 += w * u.y; a2 += w * v.x; a3 += w * v.y;
        }
    }
    for (; e + 4 <= e1; e += 4) {
        int2 p0 = csr[e], p1 = csr[e + 1], p2 = csr[e + 2], p3 = csr[e + 3];
        uint2 g0 = yin[(size_t)p0.x * ROWU2 + c4];
        uint2 g1 = yin[(size_t)p1.x * ROWU2 + c4];
        uint2 g2 = yin[(size_t)p2.x * ROWU2 + c4];
        uint2 g3 = yin[(size_t)p3.x * ROWU2 + c4];
        float w0 = __int_as_float(p0.y), w1 = __int_as_float(p1.y);
        float w2 = __int_as_float(p2.y), w3 = __int_as_float(p3.y);
        { float2 u = up2(g0.x), v = up2(g0.y); a0 += w0 * u.x; a1 += w0 * u.y; a2 += w0 * v.x; a3 += w0 * v.y; }
        { float2 u = up2(g1.x), v = up2(g1.y); a0 += w1 * u.x; a1 += w1 * u.y; a2 += w1 * v.x; a3 += w1 * v.y; }
        { float2 u = up2(g2.x), v = up2(g2.y); a0 += w2 * u.x; a1 += w2 * u.y; a2 += w2 * v.x; a3 += w2 * v.y; }
        { float2 u = up2(g3.x), v = up2(g3.y); a0 += w3 * u.x; a1 += w3 * u.y; a2 += w3 * v.x; a3 += w3 * v.y; }
    }
    for (; e < e1; e++) {
        int2 p = csr[e];
        uint2 g = yin[(size_t)p.x * ROWU2 + c4];
        float w = __int_as_float(p.y);
        float2 u = up2(g.x), v = up2(g.y);
        a0 += w * u.x; a1 += w * u.y; a2 += w * v.x; a3 += w * v.y;
    }
    // logits = dinv * acc + bias
    float4 bb = *(const float4*)(bias + c4 * 4);
    float v0 = d * a0 + bb.x, v1 = d * a1 + bb.y, v2 = d * a2 + bb.z, v3 = d * a3 + bb.w;
    // log_softmax over the node's 40 classes (10 lanes x 4)
    redm[ln][c4] = fmaxf(fmaxf(v0, v1), fmaxf(v2, v3));
    __syncthreads();
    if (c4 == 0) {
        float m = redm[ln][0];
#pragma unroll
        for (int j = 1; j < 10; j++) m = fmaxf(m, redm[ln][j]);
        redm[ln][0] = m;
    }
    __syncthreads();
    float m = redm[ln][0];
    reds[ln][c4] = __expf(v0 - m) + __expf(v1 - m) + __expf(v2 - m) + __expf(v3 - m);
    __syncthreads();
    if (c4 == 0) {
        float s = 0.f;
#pragma unroll
        for (int j = 0; j < 10; j++) s += reds[ln][j];
        reds[ln][0] = logf(s);
    }
    __syncthreads();
    float ls = reds[ln][0];
    float4 r = make_float4(v0 - m - ls, v1 - m - ls, v2 - m - ls, v3 - m - ls);
    *(float4*)(out + (size_t)n * NCLASS + c4 * 4) = r;
}

// ---------------------------------------------------------------------------
extern "C" void kernel_launch(void* const* d_in, const int* in_sizes, int n_in,
                              void* d_out, int out_size, void* d_ws, size_t ws_size,
                              hipStream_t stream) {
    const float* x = (const float*)d_in[0];
    const int* eidx = (const int*)d_in[1];
    const float* ew = (const float*)d_in[2];
    const float* W = (const float*)d_in[3];
    const float* b = (const float*)d_in[4];
    float* out = (float*)d_out;

    char* ws = (char*)d_ws;
    size_t off = 0;
    auto alloc = [&](size_t bytes) -> char* {
        char* p = ws + off;
        off += (bytes + 255) & ~(size_t)255;
        return p;
    };
    int* flag = (int*)alloc(sizeof(int));
    int* ghist = (int*)alloc((size_t)NBUCK * 4);
    int* cbase = (int*)alloc((size_t)(NBUCK + 1) * 4);
    int* cursor = (int*)alloc((size_t)NBUCK * 4);
    int* rowptr = (int*)alloc((size_t)(NNODES + 1) * 4);
    float* dinv = (float*)alloc((size_t)NNODES * 4);
    unsigned short* wt = (unsigned short*)alloc((size_t)48 * 256 * 2);
    int2* csr = (int2*)alloc((size_t)NEDGES * 8);
    // coarse buffer (25.6 MB) aliases y0h+y1h (12.8 MB each): coarse is fully
    // consumed by fine_kernel before gemm writes y0h.
    char* un = alloc((size_t)NNODES * 128 * 2);
    int2* coarse = (int2*)un;
    __half* y0h = (__half*)un;
    uint2* y1h = (uint2*)(un + (size_t)NNODES * 128);

    hipMemsetAsync(ghist, 0, (size_t)NBUCK * 4, stream);
    detect_kernel<<<1, 256, 0, stream>>>(eidx, flag);
    wconv_kernel<<<48, 256, 0, stream>>>(W, wt);
    chist_kernel<<<NCB, CSTH, 0, stream>>>(eidx, ghist, flag);
    cscan_kernel<<<1, 512, 0, stream>>>(ghist, cbase, cursor);
    cscatter_kernel<<<NCB, CSTH, 0, stream>>>(eidx, ew, coarse, cursor, flag);
    fine_kernel<<<NBUCK, 512, 0, stream>>>(coarse, cbase, rowptr, dinv, csr);
    // project features first: y0' = dinv * (x @ W.T)  (propagation commutes)
    gemm_mfma_kernel<<<(NNODES + 63) / 64, 256, 0, stream>>>(x, wt, dinv, y0h);
    // hop 1: y1' = dinv^2 (y0'[self] + A_w y0');  hop 2: out = log_softmax(dinv(...) + b)
    hop16_kernel<<<NNODES / 32, 320, 0, stream>>>(rowptr, csr, dinv, (const uint2*)y0h, y1h);
    hop32_kernel<<<NNODES / 32, 320, 0, stream>>>(rowptr, csr, dinv, y1h, b, out);
}